// Round 6
// baseline (579.977 us; speedup 1.0000x reference)
//
#include <hip/hip_runtime.h>
#include <hip/hip_bf16.h>

typedef __hip_bfloat16 bf16;
typedef __attribute__((ext_vector_type(8))) short bf16x8v;
typedef __attribute__((ext_vector_type(4))) float f32x4;

namespace {
constexpr int B_  = 2;
constexpr int C_  = 192;
constexpr int HW_ = 128 * 128;   // 16384
constexpr int C2_ = 384;
}

static __device__ __forceinline__ float fb(bf16 v) { return __bfloat162float(v); }
static __device__ __forceinline__ bf16 tob(float v) { return __float2bfloat16(v); }

typedef __attribute__((address_space(1))) const char GChar;
typedef __attribute__((address_space(3))) char LChar;
// async global->LDS, 16B per lane; LDS dest = wave-uniform base + lane*16
static __device__ __forceinline__ void gl16(const void* g, void* l) {
    __builtin_amdgcn_global_load_lds((GChar*)g, (LChar*)l, 16, 0, 0);
}
// swizzled LDS fragment read: 128B rows, 16B slots, slot ^= row&7
static __device__ __forceinline__ bf16x8v lread(const bf16* base, int row, int slot) {
    const char* p = (const char*)base + (size_t)row * 128 + ((size_t)((slot ^ (row & 7))) << 4);
    return *(const bf16x8v*)p;
}
template <int N> static __device__ __forceinline__ void vmw() {
    asm volatile("s_waitcnt vmcnt(%0)" :: "n"(N) : "memory");
}

// ---------------- weight repack: fp32 -> bf16 (optionally zero-padded) ----------------
__global__ void k_repack1(const float* __restrict__ W, bf16* __restrict__ Wr,
                          int N, int K, int Npad, int Kpad) {
    int i = blockIdx.x * 256 + threadIdx.x;
    if (i >= Npad * Kpad) return;
    int n = i / Kpad, k = i % Kpad;
    float v = (n < N && k < K) ? W[n * K + k] : 0.f;
    Wr[i] = tob(v);
}

// W[(n*K+k)*9 + q] -> Wr[(q*Npad + n)*Kpad + k]
__global__ void k_repack3(const float* __restrict__ W, bf16* __restrict__ Wr,
                          int N, int K, int Npad, int Kpad) {
    int i = blockIdx.x * 256 + threadIdx.x;
    if (i >= 9 * Npad * Kpad) return;
    int q = i / (Npad * Kpad);
    int rem = i % (Npad * Kpad);
    int n = rem / Kpad, k = rem % Kpad;
    float v = (n < N && k < K) ? W[(n * K + k) * 9 + q] : 0.f;
    Wr[i] = tob(v);
}

// ---------------- LayerNorm: NCHW fp32 -> [p][c] bf16 ----------------
__global__ __launch_bounds__(256) void k_ln_nchw(const float* __restrict__ X,
                                                 const float* __restrict__ w,
                                                 const float* __restrict__ bb,
                                                 bf16* __restrict__ out) {
    __shared__ float lds[64][C_ + 1];
    int t = threadIdx.x;
    int p0 = blockIdx.x * 64;
    int b = p0 / HW_, pi0 = p0 % HW_;
    for (int i = t; i < 64 * C_; i += 256) {
        int c = i >> 6, pp = i & 63;
        lds[pp][c] = X[((size_t)(b * C_ + c)) * HW_ + pi0 + pp];
    }
    __syncthreads();
    int pp = t >> 2, qq = t & 3;
    float s = 0.f, s2 = 0.f;
    for (int c = qq * 48; c < qq * 48 + 48; c++) { float v = lds[pp][c]; s += v; s2 += v * v; }
    s  += __shfl_xor(s, 1);  s  += __shfl_xor(s, 2);
    s2 += __shfl_xor(s2, 1); s2 += __shfl_xor(s2, 2);
    float mu = s / C_;
    float rstd = rsqrtf(s2 / C_ - mu * mu + 1e-5f);
    size_t ob = ((size_t)(p0 + pp)) * C_;
    for (int c = qq * 48; c < qq * 48 + 48; c++)
        out[ob + c] = tob((lds[pp][c] - mu) * rstd * w[c] + bb[c]);
}

// LayerNorm from [p][c] bf16 -> [p][c] bf16
__global__ __launch_bounds__(256) void k_ln_pc(const bf16* __restrict__ X2,
                                               const float* __restrict__ w,
                                               const float* __restrict__ bb,
                                               bf16* __restrict__ out) {
    int t = threadIdx.x;
    int p = blockIdx.x * 64 + (t >> 2), qq = t & 3;
    const bf16* row = X2 + (size_t)p * C_;
    float s = 0.f, s2 = 0.f;
    for (int c = qq * 48; c < qq * 48 + 48; c++) { float v = fb(row[c]); s += v; s2 += v * v; }
    s  += __shfl_xor(s, 1);  s  += __shfl_xor(s, 2);
    s2 += __shfl_xor(s2, 1); s2 += __shfl_xor(s2, 2);
    float mu = s / C_;
    float rstd = rsqrtf(s2 / C_ - mu * mu + 1e-5f);
    bf16* orow = out + (size_t)p * C_;
    for (int c = qq * 48; c < qq * 48 + 48; c++)
        orow[c] = tob((fb(row[c]) - mu) * rstd * w[c] + bb[c]);
}

// ---------------- 1x1 conv GEMM (global_load_lds + swizzle), BK=64 ----------------
// EPI: 1 = plain bf16 [p][Cout]
//      2 = +resid(NCHW f32)  -> bf16 [p][C_]
//      3 = +resid(bf16 [p][C_]) -> f32 NCHW
template <int BN, int EPI>
__global__ __launch_bounds__(256) void k_gemm1x1(const bf16* __restrict__ A,
                                                 const bf16* __restrict__ Wr,
                                                 const int K, const int Cout,
                                                 void* __restrict__ outp,
                                                 const void* __restrict__ resid) {
    constexpr int WN = BN / 2, FN = WN / 16, BIT = BN / 32;
    __shared__ __align__(16) bf16 As[128 * 64];
    __shared__ __align__(16) bf16 Bs[BN * 64];
    const int t = threadIdx.x;
    const int mt = blockIdx.x;
    const int n0 = blockIdx.y * BN;
    const int w = t >> 6, lane = t & 63;
    const int wm = w >> 1, wn = w & 1;
    const int g = lane >> 4, r = lane & 15;
    const int ldw = t - lane;  // w*64

    f32x4 acc[4][FN];
#pragma unroll
    for (int i = 0; i < 4; i++)
#pragma unroll
        for (int j = 0; j < FN; j++) acc[i][j] = {0.f, 0.f, 0.f, 0.f};

    const bf16* Abase = A + (size_t)mt * 128 * K;

    for (int c0 = 0; c0 < K; c0 += 64) {
#pragma unroll
        for (int it = 0; it < 4; it++) {
            int idx = it * 256 + t;
            int row = idx >> 3, sl = idx & 7;
            const char* gp = (const char*)(Abase + (size_t)row * K + c0) + ((sl ^ (row & 7)) << 4);
            gl16(gp, (char*)As + (size_t)(it * 256 + ldw) * 16);
        }
#pragma unroll
        for (int it = 0; it < BIT; it++) {
            int idx = it * 256 + t;
            int row = idx >> 3, sl = idx & 7;
            const char* gp = (const char*)(Wr + (size_t)(n0 + row) * K + c0) + ((sl ^ (row & 7)) << 4);
            gl16(gp, (char*)Bs + (size_t)(it * 256 + ldw) * 16);
        }
        __syncthreads();
#pragma unroll
        for (int ks = 0; ks < 2; ks++) {
            bf16x8v af[4], bv[FN];
#pragma unroll
            for (int fm = 0; fm < 4; fm++)
                af[fm] = lread(As, wm * 64 + fm * 16 + r, ks * 4 + g);
#pragma unroll
            for (int fn = 0; fn < FN; fn++)
                bv[fn] = lread(Bs, wn * WN + fn * 16 + r, ks * 4 + g);
#pragma unroll
            for (int fm = 0; fm < 4; fm++)
#pragma unroll
                for (int fn = 0; fn < FN; fn++)
                    acc[fm][fn] = __builtin_amdgcn_mfma_f32_16x16x32_bf16(af[fm], bv[fn], acc[fm][fn], 0, 0, 0);
        }
        __syncthreads();
    }

    const int b = mt >> 7, y = mt & 127;
#pragma unroll
    for (int fm = 0; fm < 4; fm++)
#pragma unroll
        for (int fn = 0; fn < FN; fn++)
#pragma unroll
            for (int reg = 0; reg < 4; reg++) {
                int xl = wm * 64 + fm * 16 + g * 4 + reg;
                int co = n0 + wn * WN + fn * 16 + r;
                float v = acc[fm][fn][reg];
                if constexpr (EPI == 1) {
                    ((bf16*)outp)[((size_t)mt * 128 + xl) * Cout + co] = tob(v);
                } else if constexpr (EPI == 2) {
                    v += ((const float*)resid)[((size_t)(b * C_ + co)) * HW_ + y * 128 + xl];
                    ((bf16*)outp)[((size_t)mt * 128 + xl) * C_ + co] = tob(v);
                } else {
                    v += fb(((const bf16*)resid)[((size_t)mt * 128 + xl) * C_ + co]);
                    ((float*)outp)[((size_t)(b * C_ + co)) * HW_ + y * 128 + xl] = v;
                }
            }
}

// ---------------- 3x3 full conv implicit GEMM, simple 2-barrier (round-4 proven) ------
// A tile: 160 rows x 64ch; B tile per kx. EPI: 0 = plain bf16, 1 = GELU bf16
template <int BN, int EPI>
__global__ __launch_bounds__(256) void k_gemm3x3(const bf16* __restrict__ A,
                                                 const bf16* __restrict__ Wr,
                                                 const int Cin, const int Cout,
                                                 bf16* __restrict__ outp,
                                                 const char* __restrict__ zpage) {
    constexpr int WN = BN / 2, FN = WN / 16, BIT = BN / 32;
    __shared__ __align__(16) bf16 As[160 * 64];
    __shared__ __align__(16) bf16 Bs[BN * 64];
    const int t = threadIdx.x;
    const int mt = blockIdx.x;
    const int n0 = blockIdx.y * BN;
    const int b = mt >> 7, y = mt & 127;
    const int w = t >> 6, lane = t & 63;
    const int wm = w >> 1, wn = w & 1;
    const int g = lane >> 4, r = lane & 15;
    const int ldw = t - lane;

    f32x4 acc[4][FN];
#pragma unroll
    for (int i = 0; i < 4; i++)
#pragma unroll
        for (int j = 0; j < FN; j++) acc[i][j] = {0.f, 0.f, 0.f, 0.f};

    for (int ky = 0; ky < 3; ky++) {
        const int yy = y + ky - 1;
        if (yy < 0 || yy > 127) continue;   // block-uniform
        const bf16* Ab = A + ((size_t)b * HW_ + (size_t)yy * 128) * Cin;
        for (int c0 = 0; c0 < Cin; c0 += 64) {
            for (int kx = 0; kx < 3; kx++) {
                if (kx == 0) {
#pragma unroll
                    for (int it = 0; it < 5; it++) {
                        int idx = it * 256 + t;
                        int row = idx >> 3, sl = idx & 7;
                        int so = (sl ^ (row & 7)) << 4;
                        const char* gp = (row >= 1 && row <= 128)
                            ? (const char*)(Ab + (size_t)(row - 1) * Cin + c0) + so
                            : zpage + so;
                        gl16(gp, (char*)As + (size_t)(it * 256 + ldw) * 16);
                    }
                }
                const bf16* Wb = Wr + (size_t)(ky * 3 + kx) * Cout * Cin;
#pragma unroll
                for (int it = 0; it < BIT; it++) {
                    int idx = it * 256 + t;
                    int row = idx >> 3, sl = idx & 7;
                    const char* gp = (const char*)(Wb + (size_t)(n0 + row) * Cin + c0) + ((sl ^ (row & 7)) << 4);
                    gl16(gp, (char*)Bs + (size_t)(it * 256 + ldw) * 16);
                }
                __syncthreads();
#pragma unroll
                for (int ks = 0; ks < 2; ks++) {
                    bf16x8v af[4], bv[FN];
#pragma unroll
                    for (int fm = 0; fm < 4; fm++)
                        af[fm] = lread(As, wm * 64 + fm * 16 + r + kx, ks * 4 + g);
#pragma unroll
                    for (int fn = 0; fn < FN; fn++)
                        bv[fn] = lread(Bs, wn * WN + fn * 16 + r, ks * 4 + g);
#pragma unroll
                    for (int fm = 0; fm < 4; fm++)
#pragma unroll
                        for (int fn = 0; fn < FN; fn++)
                            acc[fm][fn] = __builtin_amdgcn_mfma_f32_16x16x32_bf16(af[fm], bv[fn], acc[fm][fn], 0, 0, 0);
                }
                __syncthreads();
            }
        }
    }
#pragma unroll
    for (int fm = 0; fm < 4; fm++)
#pragma unroll
        for (int fn = 0; fn < FN; fn++)
#pragma unroll
            for (int reg = 0; reg < 4; reg++) {
                int xl = wm * 64 + fm * 16 + g * 4 + reg;
                int co = n0 + wn * WN + fn * 16 + r;
                float v = acc[fm][fn][reg];
                if constexpr (EPI == 1) v = 0.5f * v * (1.0f + erff(v * 0.70710678118654752f));
                outp[((size_t)mt * 128 + xl) * Cout + co] = tob(v);
            }
}

// ---------------- dw 3x3 (512->512) 8-wave phase-template pipeline --------------------
// BM=128, BN=256, BK=64. A dbuf (192-row padded tile, 24KB x2), B triple-buf (32KB x3).
// Per tap: 2 phases {8 ds_read || 2 gl16 B(s+2) [+3 gl16 A] -> bar -> 16 MFMA -> bar},
// counted vmcnt at tap end only (7/4/0). 512 threads, waves 2M x 4N, 64x64 out/wave.
__global__ __launch_bounds__(512, 1) void k_dw3x3p(const bf16* __restrict__ A,
                                                   const bf16* __restrict__ Wr,
                                                   bf16* __restrict__ outp,
                                                   const char* __restrict__ zpage) {
    constexpr int CI = 512, CO = 512, NCH = 8;
    __shared__ __align__(16) bf16 As[2][192 * 64];
    __shared__ __align__(16) bf16 Bs[3][256 * 64];
    const int t = threadIdx.x;
    const int mt = blockIdx.x;
    const int n0 = blockIdx.y * 256;
    const int b = mt >> 7, y = mt & 127;
    const int w = t >> 6, lane = t & 63;
    const int wm = w >> 2, wn = w & 3;
    const int g = lane >> 4, r = lane & 15;
    const int ldw = t - lane;

    int kys[3]; int nky = 0;
#pragma unroll
    for (int ky = 0; ky < 3; ky++) {
        int yy = y + ky - 1;
        if (yy >= 0 && yy <= 127) { kys[nky] = ky; nky++; }
    }
    const int ntri = nky * NCH;      // tri = kyi*8 + chunk
    const int nst = ntri * 3;

    f32x4 acc[4][4];
#pragma unroll
    for (int i = 0; i < 4; i++)
#pragma unroll
        for (int j = 0; j < 4; j++) acc[i][j] = {0.f, 0.f, 0.f, 0.f};

    auto stageA = [&](int tri, int buf) {   // 3 gl16/thread
        int kyi = tri >> 3, c0 = (tri & 7) * 64;
        int yy = y + kys[kyi] - 1;
        const bf16* Ab = A + ((size_t)b * HW_ + (size_t)yy * 128) * CI + c0;
#pragma unroll
        for (int it = 0; it < 3; it++) {
            int idx = it * 512 + t;
            int row = idx >> 3, sl = idx & 7;
            int so = (sl ^ (row & 7)) << 4;
            const char* gp = (row >= 1 && row <= 128)
                ? (const char*)(Ab + (size_t)(row - 1) * CI) + so
                : zpage + so;
            gl16(gp, (char*)As[buf] + (size_t)(idx - lane) * 16);
        }
    };
    auto stageBh = [&](int s, int buf, int h) {   // 2 gl16/thread per half
        int tri = s / 3, kx = s - tri * 3;
        int kyi = tri >> 3, c0 = (tri & 7) * 64;
        const bf16* Wb = Wr + (size_t)(kys[kyi] * 3 + kx) * CO * CI + c0;
#pragma unroll
        for (int it = 0; it < 2; it++) {
            int idx = (h * 2 + it) * 512 + t;
            int row = idx >> 3, sl = idx & 7;
            const char* gp = (const char*)(Wb + (size_t)(n0 + row) * CI) + ((sl ^ (row & 7)) << 4);
            gl16(gp, (char*)Bs[buf] + (size_t)(idx - lane) * 16);
        }
    };

    // prologue: A(0), B(0), B(1) in flight; need A(0)+B(0) -> leave B(1)'s 4 outstanding
    stageA(0, 0);
    stageBh(0, 0, 0); stageBh(0, 0, 1);
    stageBh(1, 1, 0); stageBh(1, 1, 1);
    vmw<4>();
    __builtin_amdgcn_s_barrier();
    __builtin_amdgcn_sched_barrier(0);

    for (int s = 0; s < nst; ++s) {
        const int tri = s / 3;
        const int kx = s - tri * 3;
        const int abuf = tri & 1, bbuf = s % 3, b2 = (s + 2) % 3;
        const bf16* Ab = As[abuf];
        const bf16* Bb = Bs[bbuf];
        const bool haveB2 = (s + 2 < nst);
        const bool issueA = (kx == 1) && (tri + 1 < ntri);
        // ---------------- phase 0 (ks=0) ----------------
        bf16x8v af0[4], bv0[4];
#pragma unroll
        for (int fm = 0; fm < 4; fm++)
            af0[fm] = lread(Ab, wm * 64 + fm * 16 + r + kx, g);
#pragma unroll
        for (int fn = 0; fn < 4; fn++)
            bv0[fn] = lread(Bb, wn * 64 + fn * 16 + r, g);
        if (haveB2) stageBh(s + 2, b2, 0);
        if (issueA) stageA(tri + 1, abuf ^ 1);
        __builtin_amdgcn_s_barrier();
        __builtin_amdgcn_sched_barrier(0);
        __builtin_amdgcn_s_setprio(1);
#pragma unroll
        for (int fm = 0; fm < 4; fm++)
#pragma unroll
            for (int fn = 0; fn < 4; fn++)
                acc[fm][fn] = __builtin_amdgcn_mfma_f32_16x16x32_bf16(af0[fm], bv0[fn], acc[fm][fn], 0, 0, 0);
        __builtin_amdgcn_s_setprio(0);
        __builtin_amdgcn_s_barrier();
        __builtin_amdgcn_sched_barrier(0);
        // ---------------- phase 1 (ks=1) ----------------
        bf16x8v af1[4], bv1[4];
#pragma unroll
        for (int fm = 0; fm < 4; fm++)
            af1[fm] = lread(Ab, wm * 64 + fm * 16 + r + kx, 4 + g);
#pragma unroll
        for (int fn = 0; fn < 4; fn++)
            bv1[fn] = lread(Bb, wn * 64 + fn * 16 + r, 4 + g);
        if (haveB2) stageBh(s + 2, b2, 1);
        __builtin_amdgcn_s_barrier();
        __builtin_amdgcn_sched_barrier(0);
        __builtin_amdgcn_s_setprio(1);
#pragma unroll
        for (int fm = 0; fm < 4; fm++)
#pragma unroll
            for (int fn = 0; fn < 4; fn++)
                acc[fm][fn] = __builtin_amdgcn_mfma_f32_16x16x32_bf16(af1[fm], bv1[fn], acc[fm][fn], 0, 0, 0);
        __builtin_amdgcn_s_setprio(0);
        if (s + 1 == nst) break;
        // counted tap-end wait: outstanding after wait = issues made during this tap
        if (haveB2) { if (issueA) vmw<7>(); else vmw<4>(); }
        else vmw<0>();
        __builtin_amdgcn_s_barrier();
        __builtin_amdgcn_sched_barrier(0);
    }

#pragma unroll
    for (int fm = 0; fm < 4; fm++)
#pragma unroll
        for (int fn = 0; fn < 4; fn++)
#pragma unroll
            for (int reg = 0; reg < 4; reg++) {
                int xl = wm * 64 + fm * 16 + g * 4 + reg;
                int co = n0 + wn * 64 + fn * 16 + r;
                float v = acc[fm][fn][reg];
                v = 0.5f * v * (1.0f + erff(v * 0.70710678118654752f));   // GELU
                outp[((size_t)mt * 128 + xl) * CO + co] = tob(v);
            }
}

// ---------------- depthwise 3x3: weights in LDS->VGPR, 16 x-positions per thread -------
__global__ __launch_bounds__(192) void k_dwconv2(const bf16* __restrict__ kv,
                                                 const float* __restrict__ wdw,
                                                 bf16* __restrict__ kout,
                                                 bf16* __restrict__ vout) {
    __shared__ float wlds[1728];
    const int t = threadIdx.x;
    const int row = blockIdx.x;
    const int z = blockIdx.y;
    const int b = row >> 7, y = row & 127;
    for (int i = t; i < 432; i += 192)
        ((float4*)wlds)[i] = ((const float4*)(wdw + (size_t)z * 1728))[i];
    __syncthreads();
    const int c8h = t % 24, xg = t / 24;
    const int cbase = z * C_ + c8h * 8;
    float wreg[9][8];
#pragma unroll
    for (int tap = 0; tap < 9; tap++)
#pragma unroll
        for (int j = 0; j < 8; j++) wreg[tap][j] = wlds[(c8h * 8 + j) * 9 + tap];

    bf16* outb = (z == 0 ? kout : vout) + (size_t)(b * HW_ + y * 128) * C_ + c8h * 8;
    const uint4 zero4 = make_uint4(0u, 0u, 0u, 0u);
    for (int i = 0; i < 16; i++) {
        int x = xg + 8 * i;
        float acc[8];
#pragma unroll
        for (int j = 0; j < 8; j++) acc[j] = 0.f;
#pragma unroll
        for (int ky = 0; ky < 3; ky++) {
            int yy = y + ky - 1;
            if (yy < 0 || yy > 127) continue;
            const bf16* rb = kv + ((size_t)b * HW_ + (size_t)yy * 128) * C2_ + cbase;
#pragma unroll
            for (int kx = 0; kx < 3; kx++) {
                int xx = x + kx - 1;
                uint4 vv = (xx >= 0 && xx <= 127) ? *(const uint4*)(rb + (size_t)xx * C2_) : zero4;
                const bf16* pv = (const bf16*)&vv;
#pragma unroll
                for (int j = 0; j < 8; j++)
                    acc[j] += fb(pv[j]) * wreg[ky * 3 + kx][j];
            }
        }
        union { bf16 h[8]; uint4 u; } ov;
#pragma unroll
        for (int j = 0; j < 8; j++) ov.h[j] = tob(acc[j]);
        *(uint4*)(outb + (size_t)x * C_) = ov.u;
    }
}

// ---------------- deterministic per-(sel,b,c) sum-of-squares partials (vectorized) -----
__global__ __launch_bounds__(192) void k_ssqpart(const bf16* __restrict__ q,
                                                 const bf16* __restrict__ k,
                                                 float* __restrict__ ssq) {
    __shared__ float red[192][8];
    int t = threadIdx.x;
    int c8 = t % 24, slot = t / 24;
    int ch = blockIdx.x, b = blockIdx.y, sel = blockIdx.z;
    const bf16* src = (sel ? k : q) + ((size_t)b * HW_ + ch * 256) * C_ + c8 * 8;
    float s[8];
#pragma unroll
    for (int j = 0; j < 8; j++) s[j] = 0.f;
    for (int i = slot; i < 256; i += 8) {
        uint4 v = *(const uint4*)(src + (size_t)i * C_);
        const bf16* pv = (const bf16*)&v;
#pragma unroll
        for (int j = 0; j < 8; j++) { float x = fb(pv[j]); s[j] += x * x; }
    }
#pragma unroll
    for (int j = 0; j < 8; j++) red[t][j] = s[j];
    __syncthreads();
    if (slot == 0) {
        float o[8];
#pragma unroll
        for (int j = 0; j < 8; j++) o[j] = 0.f;
        for (int ss = 0; ss < 8; ss++)
#pragma unroll
            for (int j = 0; j < 8; j++) o[j] += red[c8 + 24 * ss][j];
        float* dst = ssq + (((size_t)(sel * 2 + b)) * 64 + ch) * C_ + c8 * 8;
#pragma unroll
        for (int j = 0; j < 8; j++) dst[j] = o[j];
    }
}

__global__ void k_inv(const float* __restrict__ ssq, float* __restrict__ inv) {
    int i = blockIdx.x * 256 + threadIdx.x;
    if (i >= 768) return;
    int sb = i / C_, c = i % C_;
    float s = 0.f;
    for (int ch = 0; ch < 64; ch++) s += ssq[((size_t)sb * 64 + ch) * C_ + c];
    inv[i] = 1.f / fmaxf(sqrtf(s), 1e-12f);
}

// ---------------- S partials: per (b,hd,chunk) 48x48 over 1024 positions ----------------
__global__ __launch_bounds__(256) void k_qk(const bf16* __restrict__ q,
                                            const bf16* __restrict__ k,
                                            float* __restrict__ Spart) {
    __shared__ float qs[64][49];
    __shared__ float ks[64][49];
    int t = threadIdx.x;
    int ch = blockIdx.x, hd = blockIdx.y, b = blockIdx.z;
    int i0 = (t >> 4) * 3, j0 = (t & 15) * 3;
    float acc[3][3];
#pragma unroll
    for (int a = 0; a < 3; a++)
#pragma unroll
        for (int c = 0; c < 3; c++) acc[a][c] = 0.f;

    for (int sub = 0; sub < 16; sub++) {
        size_t rbase = ((size_t)b * HW_ + ch * 1024 + sub * 64) * C_ + hd * 48;
        for (int i = t; i < 64 * 6; i += 256) {
            int row = i / 6, oc = i % 6;
            uint4 v = *(const uint4*)(q + rbase + (size_t)row * C_ + oc * 8);
            const bf16* pv = (const bf16*)&v;
#pragma unroll
            for (int j = 0; j < 8; j++) qs[row][oc * 8 + j] = fb(pv[j]);
            uint4 v2 = *(const uint4*)(k + rbase + (size_t)row * C_ + oc * 8);
            const bf16* pv2 = (const bf16*)&v2;
#pragma unroll
            for (int j = 0; j < 8; j++) ks[row][oc * 8 + j] = fb(pv2[j]);
        }
        __syncthreads();
        for (int p = 0; p < 64; p++) {
            float a0 = qs[p][i0], a1 = qs[p][i0 + 1], a2 = qs[p][i0 + 2];
            float b0 = ks[p][j0], b1 = ks[p][j0 + 1], b2 = ks[p][j0 + 2];
            acc[0][0] += a0 * b0; acc[0][1] += a0 * b1; acc[0][2] += a0 * b2;
            acc[1][0] += a1 * b0; acc[1][1] += a1 * b1; acc[1][2] += a1 * b2;
            acc[2][0] += a2 * b0; acc[2][1] += a2 * b1; acc[2][2] += a2 * b2;
        }
        __syncthreads();
    }
    float* dst = Spart + (((size_t)(b * 4 + hd)) * 16 + ch) * 2304;
#pragma unroll
    for (int a = 0; a < 3; a++)
#pragma unroll
        for (int c = 0; c < 3; c++) dst[(i0 + a) * 48 + (j0 + c)] = acc[a][c];
}

__global__ void k_softmax(const float* __restrict__ Spart, const float* __restrict__ invq,
                          const float* __restrict__ invk, const float* __restrict__ temp,
                          float* __restrict__ attn) {
    int t = threadIdx.x;
    if (t >= 48) return;
    int hd = blockIdx.x, b = blockIdx.y;
    const float* base = Spart + ((size_t)(b * 4 + hd)) * 16 * 2304;
    float qi = invq[b * C_ + hd * 48 + t];
    float tp = temp[hd];
    float row[48];
    float mx = -1e30f;
    for (int j = 0; j < 48; j++) {
        float s = 0.f;
        for (int ch = 0; ch < 16; ch++) s += base[ch * 2304 + t * 48 + j];
        s *= qi * invk[b * C_ + hd * 48 + j] * tp;
        row[j] = s;
        mx = fmaxf(mx, s);
    }
    float sum = 0.f;
    for (int j = 0; j < 48; j++) { row[j] = expf(row[j] - mx); sum += row[j]; }
    float is = 1.f / sum;
    for (int j = 0; j < 48; j++)
        attn[(((size_t)(b * 4 + hd)) * 48 + t) * 48 + j] = row[j] * is;
}

// ---------------- out = attn @ v  (per position, per head) ----------------
__global__ __launch_bounds__(256) void k_av(const float* __restrict__ attn,
                                            const bf16* __restrict__ v,
                                            bf16* __restrict__ out) {
    __shared__ float As[4 * 48 * 48];
    int t = threadIdx.x;
    int b = blockIdx.y;
    for (int i = t; i < 9216; i += 256) As[i] = attn[(size_t)b * 9216 + i];
    __syncthreads();
    int p = blockIdx.x * 64 + (t >> 2);
    int hd = t & 3;
    size_t row = (size_t)b * HW_ + p;
    const float* am = As + hd * 2304;
    float acc[48];
#pragma unroll
    for (int i = 0; i < 48; i++) acc[i] = 0.f;
#pragma unroll
    for (int jo = 0; jo < 6; jo++) {
        uint4 vv = *(const uint4*)(v + row * C_ + hd * 48 + jo * 8);
        const bf16* pv = (const bf16*)&vv;
#pragma unroll
        for (int jj = 0; jj < 8; jj++) {
            float vj = fb(pv[jj]);
            int j = jo * 8 + jj;
#pragma unroll
            for (int i = 0; i < 48; i++) acc[i] += am[i * 48 + j] * vj;
        }
    }
#pragma unroll
    for (int io = 0; io < 6; io++) {
        union { bf16 h[8]; uint4 u; } ov;
#pragma unroll
        for (int jj = 0; jj < 8; jj++) ov.h[jj] = tob(acc[io * 8 + jj]);
        *(uint4*)(out + row * C_ + hd * 48 + io * 8) = ov.u;
    }
}

// =====================================================================================
extern "C" void kernel_launch(void* const* d_in, const int* in_sizes, int n_in,
                              void* d_out, int out_size, void* d_ws, size_t ws_size,
                              hipStream_t stream) {
    const float* x     = (const float*)d_in[0];
    const float* illum = (const float*)d_in[1];
    const float* ln1w  = (const float*)d_in[2];
    const float* ln1b  = (const float*)d_in[3];
    const float* lnLw  = (const float*)d_in[4];
    const float* lnLb  = (const float*)d_in[5];
    const float* ln2w  = (const float*)d_in[6];
    const float* ln2b  = (const float*)d_in[7];
    const float* qw    = (const float*)d_in[8];
    const float* qdww  = (const float*)d_in[9];
    const float* kvw   = (const float*)d_in[10];
    const float* kvdww = (const float*)d_in[11];
    const float* temp  = (const float*)d_in[12];
    const float* projw = (const float*)d_in[13];
    const float* pinw  = (const float*)d_in[14];
    const float* dww   = (const float*)d_in[15];
    const float* poutw = (const float*)d_in[16];

    char* ws = (char*)d_ws;
    bf16*  Wq1   = (bf16*)(ws + 0);
    bf16*  Wkv   = (bf16*)(ws + 73728);
    bf16*  Wqdw  = (bf16*)(ws + 221184);
    bf16*  Wproj = (bf16*)(ws + 884736);
    bf16*  Wpin  = (bf16*)(ws + 958464);
    bf16*  Wdw   = (bf16*)(ws + 1155072);
    bf16*  Wpout = (bf16*)(ws + 5873664);
    float* Spart = (float*)(ws + 6070272);
    float* attn  = (float*)(ws + 7249920);
    float* ssq   = (float*)(ws + 7323648);
    float* invv  = (float*)(ws + 7520256);
    char*  zpage = (char*)(ws + 7523328);
    const size_t A0 = 7527424, u = 12582912;
    bf16* xn    = (bf16*)(ws + A0 + 0 * u);
    bf16* iln   = (bf16*)(ws + A0 + 1 * u);
    bf16* qtmp  = (bf16*)(ws + A0 + 2 * u);
    bf16* qb    = (bf16*)(ws + A0 + 1 * u);
    bf16* kvtmp = (bf16*)(ws + A0 + 2 * u);
    bf16* kb    = (bf16*)(ws + A0 + 0 * u);
    bf16* vb    = (bf16*)(ws + A0 + 4 * u);
    bf16* outa  = (bf16*)(ws + A0 + 2 * u);
    bf16* x2    = (bf16*)(ws + A0 + 0 * u);
    bf16* xn2   = (bf16*)(ws + A0 + 3 * u);
    bf16* fbuf  = (bf16*)(ws + A0 + 4 * u);
    bf16* gbuf  = (bf16*)(ws + A0 + 1 * u);

    hipMemsetAsync(zpage, 0, 4096, stream);

    k_repack1<<<(192 * 192 + 255) / 256, 256, 0, stream>>>(qw, Wq1, 192, 192, 192, 192);
    k_repack1<<<(384 * 192 + 255) / 256, 256, 0, stream>>>(kvw, Wkv, 384, 192, 384, 192);
    k_repack3<<<(9 * 192 * 192 + 255) / 256, 256, 0, stream>>>(qdww, Wqdw, 192, 192, 192, 192);
    k_repack1<<<(192 * 192 + 255) / 256, 256, 0, stream>>>(projw, Wproj, 192, 192, 192, 192);
    k_repack1<<<(512 * 192 + 255) / 256, 256, 0, stream>>>(pinw, Wpin, 510, 192, 512, 192);
    k_repack3<<<(9 * 512 * 512 + 255) / 256, 256, 0, stream>>>(dww, Wdw, 510, 510, 512, 512);
    k_repack1<<<(192 * 512 + 255) / 256, 256, 0, stream>>>(poutw, Wpout, 192, 510, 192, 512);

    k_ln_nchw<<<512, 256, 0, stream>>>(x, ln1w, ln1b, xn);
    k_ln_nchw<<<512, 256, 0, stream>>>(illum, lnLw, lnLb, iln);

    k_gemm1x1<96, 1><<<dim3(256, 2), 256, 0, stream>>>(iln, Wq1, 192, 192, qtmp, nullptr);
    k_gemm3x3<96, 0><<<dim3(256, 2), 256, 0, stream>>>(qtmp, Wqdw, 192, 192, qb, zpage);

    k_gemm1x1<128, 1><<<dim3(256, 3), 256, 0, stream>>>(xn, Wkv, 192, 384, kvtmp, nullptr);
    k_dwconv2<<<dim3(256, 2), 192, 0, stream>>>(kvtmp, kvdww, kb, vb);

    k_ssqpart<<<dim3(64, 2, 2), 192, 0, stream>>>(qb, kb, ssq);
    k_inv<<<3, 256, 0, stream>>>(ssq, invv);
    k_qk<<<dim3(16, 4, 2), 256, 0, stream>>>(qb, kb, Spart);
    k_softmax<<<dim3(4, 2), 64, 0, stream>>>(Spart, invv, invv + 384, temp, attn);
    k_av<<<dim3(256, 2), 256, 0, stream>>>(attn, vb, outa);

    k_gemm1x1<96, 2><<<dim3(256, 2), 256, 0, stream>>>(outa, Wproj, 192, 192, x2, x);

    k_ln_pc<<<512, 256, 0, stream>>>(x2, ln2w, ln2b, xn2);
    k_gemm1x1<128, 1><<<dim3(256, 4), 256, 0, stream>>>(xn2, Wpin, 192, 512, fbuf, nullptr);
    k_dw3x3p<<<dim3(256, 2), 512, 0, stream>>>(fbuf, Wdw, gbuf, zpage);
    k_gemm1x1<96, 3><<<dim3(256, 2), 256, 0, stream>>>(gbuf, Wpout, 512, 192, d_out, x2);
}

// Round 7
// 493.091 us; speedup vs baseline: 1.1762x; 1.1762x over previous
//
#include <hip/hip_runtime.h>
#include <hip/hip_bf16.h>

typedef __hip_bfloat16 bf16;
typedef __attribute__((ext_vector_type(8))) short bf16x8v;
typedef __attribute__((ext_vector_type(4))) float f32x4;

namespace {
constexpr int B_  = 2;
constexpr int C_  = 192;
constexpr int HW_ = 128 * 128;   // 16384
constexpr int C2_ = 384;
}

static __device__ __forceinline__ float fb(bf16 v) { return __bfloat162float(v); }
static __device__ __forceinline__ bf16 tob(float v) { return __float2bfloat16(v); }

typedef __attribute__((address_space(1))) const char GChar;
typedef __attribute__((address_space(3))) char LChar;
// async global->LDS, 16B per lane; LDS dest = wave-uniform base + lane*16
static __device__ __forceinline__ void gl16(const void* g, void* l) {
    __builtin_amdgcn_global_load_lds((GChar*)g, (LChar*)l, 16, 0, 0);
}
// swizzled LDS fragment read: 128B rows, 16B slots, slot ^= row&7
static __device__ __forceinline__ bf16x8v lread(const bf16* base, int row, int slot) {
    const char* p = (const char*)base + (size_t)row * 128 + ((size_t)((slot ^ (row & 7))) << 4);
    return *(const bf16x8v*)p;
}

// ---------------- fused weight repack + zero page (one kernel, range dispatch) ---------
static __device__ __forceinline__ void rp1(const float* W, bf16* Wr, int blk, int t,
                                           int N, int K, int Npad, int Kpad) {
    int i = blk * 256 + t;
    if (i >= Npad * Kpad) return;
    int n = i / Kpad, k = i % Kpad;
    float v = (n < N && k < K) ? W[n * K + k] : 0.f;
    Wr[i] = tob(v);
}
static __device__ __forceinline__ void rp3(const float* W, bf16* Wr, int blk, int t,
                                           int N, int K, int Npad, int Kpad) {
    int i = blk * 256 + t;
    if (i >= 9 * Npad * Kpad) return;
    int q = i / (Npad * Kpad);
    int rem = i % (Npad * Kpad);
    int n = rem / Kpad, k = rem % Kpad;
    float v = (n < N && k < K) ? W[(n * K + k) * 9 + q] : 0.f;
    Wr[i] = tob(v);
}
__global__ __launch_bounds__(256) void k_repack_all(
    const float* __restrict__ qw, const float* __restrict__ kvw,
    const float* __restrict__ projw, const float* __restrict__ pinw,
    const float* __restrict__ poutw, const float* __restrict__ qdww,
    const float* __restrict__ dww,
    bf16* __restrict__ Wq1, bf16* __restrict__ Wkv, bf16* __restrict__ Wproj,
    bf16* __restrict__ Wpin, bf16* __restrict__ Wpout, bf16* __restrict__ Wqdw,
    bf16* __restrict__ Wdw, char* __restrict__ zpage) {
    int blk = blockIdx.x, t = threadIdx.x;
    if (blk < 144)        rp1(qw,    Wq1,   blk,         t, 192, 192, 192, 192);
    else if (blk < 432)   rp1(kvw,   Wkv,   blk - 144,   t, 384, 192, 384, 192);
    else if (blk < 576)   rp1(projw, Wproj, blk - 432,   t, 192, 192, 192, 192);
    else if (blk < 960)   rp1(pinw,  Wpin,  blk - 576,   t, 510, 192, 512, 192);
    else if (blk < 1344)  rp1(poutw, Wpout, blk - 960,   t, 192, 510, 192, 512);
    else if (blk < 2640)  rp3(qdww,  Wqdw,  blk - 1344,  t, 192, 192, 192, 192);
    else if (blk < 11856) rp3(dww,   Wdw,   blk - 2640,  t, 510, 510, 512, 512);
    else ((uint4*)zpage)[t] = make_uint4(0u, 0u, 0u, 0u);
}

// ---------------- LayerNorm: NCHW fp32 -> [p][c] bf16 (fused pair via grid.z) ----------
__global__ __launch_bounds__(256) void k_ln_nchw(const float* __restrict__ X0,
                                                 const float* __restrict__ X1,
                                                 const float* __restrict__ w0,
                                                 const float* __restrict__ b0,
                                                 const float* __restrict__ w1,
                                                 const float* __restrict__ b1,
                                                 bf16* __restrict__ out0,
                                                 bf16* __restrict__ out1) {
    const float* X = blockIdx.y ? X1 : X0;
    const float* w = blockIdx.y ? w1 : w0;
    const float* bb = blockIdx.y ? b1 : b0;
    bf16* out = blockIdx.y ? out1 : out0;
    __shared__ float lds[64][C_ + 1];
    int t = threadIdx.x;
    int p0 = blockIdx.x * 64;
    int b = p0 / HW_, pi0 = p0 % HW_;
    for (int i = t; i < 64 * C_; i += 256) {
        int c = i >> 6, pp = i & 63;
        lds[pp][c] = X[((size_t)(b * C_ + c)) * HW_ + pi0 + pp];
    }
    __syncthreads();
    int pp = t >> 2, qq = t & 3;
    float s = 0.f, s2 = 0.f;
    for (int c = qq * 48; c < qq * 48 + 48; c++) { float v = lds[pp][c]; s += v; s2 += v * v; }
    s  += __shfl_xor(s, 1);  s  += __shfl_xor(s, 2);
    s2 += __shfl_xor(s2, 1); s2 += __shfl_xor(s2, 2);
    float mu = s / C_;
    float rstd = rsqrtf(s2 / C_ - mu * mu + 1e-5f);
    size_t ob = ((size_t)(p0 + pp)) * C_;
    for (int c = qq * 48; c < qq * 48 + 48; c++)
        out[ob + c] = tob((lds[pp][c] - mu) * rstd * w[c] + bb[c]);
}

// LayerNorm from [p][c] bf16 -> [p][c] bf16
__global__ __launch_bounds__(256) void k_ln_pc(const bf16* __restrict__ X2,
                                               const float* __restrict__ w,
                                               const float* __restrict__ bb,
                                               bf16* __restrict__ out) {
    int t = threadIdx.x;
    int p = blockIdx.x * 64 + (t >> 2), qq = t & 3;
    const bf16* row = X2 + (size_t)p * C_;
    float s = 0.f, s2 = 0.f;
    for (int c = qq * 48; c < qq * 48 + 48; c++) { float v = fb(row[c]); s += v; s2 += v * v; }
    s  += __shfl_xor(s, 1);  s  += __shfl_xor(s, 2);
    s2 += __shfl_xor(s2, 1); s2 += __shfl_xor(s2, 2);
    float mu = s / C_;
    float rstd = rsqrtf(s2 / C_ - mu * mu + 1e-5f);
    bf16* orow = out + (size_t)p * C_;
    for (int c = qq * 48; c < qq * 48 + 48; c++)
        orow[c] = tob((fb(row[c]) - mu) * rstd * w[c] + bb[c]);
}

// ---------------- 1x1 conv GEMM (global_load_lds + swizzle), BK=64 ----------------
// EPI: 1 = plain bf16 [p][Cout]
//      2 = +resid(NCHW f32)  -> bf16 [p][C_]
//      3 = +resid(bf16 [p][C_]) -> f32 NCHW
template <int BN, int EPI>
__global__ __launch_bounds__(256) void k_gemm1x1(const bf16* __restrict__ A,
                                                 const bf16* __restrict__ Wr,
                                                 const int K, const int Cout,
                                                 void* __restrict__ outp,
                                                 const void* __restrict__ resid) {
    constexpr int WN = BN / 2, FN = WN / 16, BIT = BN / 32;
    __shared__ __align__(16) bf16 As[128 * 64];
    __shared__ __align__(16) bf16 Bs[BN * 64];
    const int t = threadIdx.x;
    const int mt = blockIdx.x;
    const int n0 = blockIdx.y * BN;
    const int w = t >> 6, lane = t & 63;
    const int wm = w >> 1, wn = w & 1;
    const int g = lane >> 4, r = lane & 15;
    const int ldw = t - lane;  // w*64

    f32x4 acc[4][FN];
#pragma unroll
    for (int i = 0; i < 4; i++)
#pragma unroll
        for (int j = 0; j < FN; j++) acc[i][j] = {0.f, 0.f, 0.f, 0.f};

    const bf16* Abase = A + (size_t)mt * 128 * K;

    for (int c0 = 0; c0 < K; c0 += 64) {
#pragma unroll
        for (int it = 0; it < 4; it++) {
            int idx = it * 256 + t;
            int row = idx >> 3, sl = idx & 7;
            const char* gp = (const char*)(Abase + (size_t)row * K + c0) + ((sl ^ (row & 7)) << 4);
            gl16(gp, (char*)As + (size_t)(it * 256 + ldw) * 16);
        }
#pragma unroll
        for (int it = 0; it < BIT; it++) {
            int idx = it * 256 + t;
            int row = idx >> 3, sl = idx & 7;
            const char* gp = (const char*)(Wr + (size_t)(n0 + row) * K + c0) + ((sl ^ (row & 7)) << 4);
            gl16(gp, (char*)Bs + (size_t)(it * 256 + ldw) * 16);
        }
        __syncthreads();
#pragma unroll
        for (int ks = 0; ks < 2; ks++) {
            bf16x8v af[4], bv[FN];
#pragma unroll
            for (int fm = 0; fm < 4; fm++)
                af[fm] = lread(As, wm * 64 + fm * 16 + r, ks * 4 + g);
#pragma unroll
            for (int fn = 0; fn < FN; fn++)
                bv[fn] = lread(Bs, wn * WN + fn * 16 + r, ks * 4 + g);
#pragma unroll
            for (int fm = 0; fm < 4; fm++)
#pragma unroll
                for (int fn = 0; fn < FN; fn++)
                    acc[fm][fn] = __builtin_amdgcn_mfma_f32_16x16x32_bf16(af[fm], bv[fn], acc[fm][fn], 0, 0, 0);
        }
        __syncthreads();
    }

    const int b = mt >> 7, y = mt & 127;
#pragma unroll
    for (int fm = 0; fm < 4; fm++)
#pragma unroll
        for (int fn = 0; fn < FN; fn++)
#pragma unroll
            for (int reg = 0; reg < 4; reg++) {
                int xl = wm * 64 + fm * 16 + g * 4 + reg;
                int co = n0 + wn * WN + fn * 16 + r;
                float v = acc[fm][fn][reg];
                if constexpr (EPI == 1) {
                    ((bf16*)outp)[((size_t)mt * 128 + xl) * Cout + co] = tob(v);
                } else if constexpr (EPI == 2) {
                    v += ((const float*)resid)[((size_t)(b * C_ + co)) * HW_ + y * 128 + xl];
                    ((bf16*)outp)[((size_t)mt * 128 + xl) * C_ + co] = tob(v);
                } else {
                    v += fb(((const bf16*)resid)[((size_t)mt * 128 + xl) * C_ + co]);
                    ((float*)outp)[((size_t)(b * C_ + co)) * HW_ + y * 128 + xl] = v;
                }
            }
}

// ---------------- 3x3 full conv implicit GEMM, simple 2-barrier + XCD mt-swizzle ------
// A tile: 160 rows x 64ch; B tile per kx. EPI: 0 = plain bf16, 1 = GELU bf16
// mt swizzle: 32 consecutive output rows per XCD -> A rows L2-local (grid.x must be 256)
template <int BN, int EPI>
__global__ __launch_bounds__(256) void k_gemm3x3(const bf16* __restrict__ A,
                                                 const bf16* __restrict__ Wr,
                                                 const int Cin, const int Cout,
                                                 bf16* __restrict__ outp,
                                                 const char* __restrict__ zpage) {
    constexpr int WN = BN / 2, FN = WN / 16, BIT = BN / 32;
    __shared__ __align__(16) bf16 As[160 * 64];
    __shared__ __align__(16) bf16 Bs[BN * 64];
    const int t = threadIdx.x;
    const int mtRaw = blockIdx.x;
    const int mt = ((mtRaw & 7) << 5) | (mtRaw >> 3);   // XCD-contiguous rows
    const int n0 = blockIdx.y * BN;
    const int b = mt >> 7, y = mt & 127;
    const int w = t >> 6, lane = t & 63;
    const int wm = w >> 1, wn = w & 1;
    const int g = lane >> 4, r = lane & 15;
    const int ldw = t - lane;

    f32x4 acc[4][FN];
#pragma unroll
    for (int i = 0; i < 4; i++)
#pragma unroll
        for (int j = 0; j < FN; j++) acc[i][j] = {0.f, 0.f, 0.f, 0.f};

    for (int ky = 0; ky < 3; ky++) {
        const int yy = y + ky - 1;
        if (yy < 0 || yy > 127) continue;   // block-uniform
        const bf16* Ab = A + ((size_t)b * HW_ + (size_t)yy * 128) * Cin;
        for (int c0 = 0; c0 < Cin; c0 += 64) {
            for (int kx = 0; kx < 3; kx++) {
                if (kx == 0) {
#pragma unroll
                    for (int it = 0; it < 5; it++) {
                        int idx = it * 256 + t;
                        int row = idx >> 3, sl = idx & 7;
                        int so = (sl ^ (row & 7)) << 4;
                        const char* gp = (row >= 1 && row <= 128)
                            ? (const char*)(Ab + (size_t)(row - 1) * Cin + c0) + so
                            : zpage + so;
                        gl16(gp, (char*)As + (size_t)(it * 256 + ldw) * 16);
                    }
                }
                const bf16* Wb = Wr + (size_t)(ky * 3 + kx) * Cout * Cin;
#pragma unroll
                for (int it = 0; it < BIT; it++) {
                    int idx = it * 256 + t;
                    int row = idx >> 3, sl = idx & 7;
                    const char* gp = (const char*)(Wb + (size_t)(n0 + row) * Cin + c0) + ((sl ^ (row & 7)) << 4);
                    gl16(gp, (char*)Bs + (size_t)(it * 256 + ldw) * 16);
                }
                __syncthreads();
#pragma unroll
                for (int ks = 0; ks < 2; ks++) {
                    bf16x8v af[4], bv[FN];
#pragma unroll
                    for (int fm = 0; fm < 4; fm++)
                        af[fm] = lread(As, wm * 64 + fm * 16 + r + kx, ks * 4 + g);
#pragma unroll
                    for (int fn = 0; fn < FN; fn++)
                        bv[fn] = lread(Bs, wn * WN + fn * 16 + r, ks * 4 + g);
#pragma unroll
                    for (int fm = 0; fm < 4; fm++)
#pragma unroll
                        for (int fn = 0; fn < FN; fn++)
                            acc[fm][fn] = __builtin_amdgcn_mfma_f32_16x16x32_bf16(af[fm], bv[fn], acc[fm][fn], 0, 0, 0);
                }
                __syncthreads();
            }
        }
    }
#pragma unroll
    for (int fm = 0; fm < 4; fm++)
#pragma unroll
        for (int fn = 0; fn < FN; fn++)
#pragma unroll
            for (int reg = 0; reg < 4; reg++) {
                int xl = wm * 64 + fm * 16 + g * 4 + reg;
                int co = n0 + wn * WN + fn * 16 + r;
                float v = acc[fm][fn][reg];
                if constexpr (EPI == 1) v = 0.5f * v * (1.0f + erff(v * 0.70710678118654752f));
                outp[((size_t)mt * 128 + xl) * Cout + co] = tob(v);
            }
}

// ---------------- depthwise 3x3: weights in LDS->VGPR, 16 x-positions per thread -------
__global__ __launch_bounds__(192) void k_dwconv2(const bf16* __restrict__ kv,
                                                 const float* __restrict__ wdw,
                                                 bf16* __restrict__ kout,
                                                 bf16* __restrict__ vout) {
    __shared__ float wlds[1728];
    const int t = threadIdx.x;
    const int row = blockIdx.x;
    const int z = blockIdx.y;
    const int b = row >> 7, y = row & 127;
    for (int i = t; i < 432; i += 192)
        ((float4*)wlds)[i] = ((const float4*)(wdw + (size_t)z * 1728))[i];
    __syncthreads();
    const int c8h = t % 24, xg = t / 24;
    const int cbase = z * C_ + c8h * 8;
    float wreg[9][8];
#pragma unroll
    for (int tap = 0; tap < 9; tap++)
#pragma unroll
        for (int j = 0; j < 8; j++) wreg[tap][j] = wlds[(c8h * 8 + j) * 9 + tap];

    bf16* outb = (z == 0 ? kout : vout) + (size_t)(b * HW_ + y * 128) * C_ + c8h * 8;
    const uint4 zero4 = make_uint4(0u, 0u, 0u, 0u);
    for (int i = 0; i < 16; i++) {
        int x = xg + 8 * i;
        float acc[8];
#pragma unroll
        for (int j = 0; j < 8; j++) acc[j] = 0.f;
#pragma unroll
        for (int ky = 0; ky < 3; ky++) {
            int yy = y + ky - 1;
            if (yy < 0 || yy > 127) continue;
            const bf16* rb = kv + ((size_t)b * HW_ + (size_t)yy * 128) * C2_ + cbase;
#pragma unroll
            for (int kx = 0; kx < 3; kx++) {
                int xx = x + kx - 1;
                uint4 vv = (xx >= 0 && xx <= 127) ? *(const uint4*)(rb + (size_t)xx * C2_) : zero4;
                const bf16* pv = (const bf16*)&vv;
#pragma unroll
                for (int j = 0; j < 8; j++)
                    acc[j] += fb(pv[j]) * wreg[ky * 3 + kx][j];
            }
        }
        union { bf16 h[8]; uint4 u; } ov;
#pragma unroll
        for (int j = 0; j < 8; j++) ov.h[j] = tob(acc[j]);
        *(uint4*)(outb + (size_t)x * C_) = ov.u;
    }
}

// ---------------- deterministic per-(sel,b,c) sum-of-squares partials (vectorized) -----
__global__ __launch_bounds__(192) void k_ssqpart(const bf16* __restrict__ q,
                                                 const bf16* __restrict__ k,
                                                 float* __restrict__ ssq) {
    __shared__ float red[192][8];
    int t = threadIdx.x;
    int c8 = t % 24, slot = t / 24;
    int ch = blockIdx.x, b = blockIdx.y, sel = blockIdx.z;
    const bf16* src = (sel ? k : q) + ((size_t)b * HW_ + ch * 256) * C_ + c8 * 8;
    float s[8];
#pragma unroll
    for (int j = 0; j < 8; j++) s[j] = 0.f;
    for (int i = slot; i < 256; i += 8) {
        uint4 v = *(const uint4*)(src + (size_t)i * C_);
        const bf16* pv = (const bf16*)&v;
#pragma unroll
        for (int j = 0; j < 8; j++) { float x = fb(pv[j]); s[j] += x * x; }
    }
#pragma unroll
    for (int j = 0; j < 8; j++) red[t][j] = s[j];
    __syncthreads();
    if (slot == 0) {
        float o[8];
#pragma unroll
        for (int j = 0; j < 8; j++) o[j] = 0.f;
        for (int ss = 0; ss < 8; ss++)
#pragma unroll
            for (int j = 0; j < 8; j++) o[j] += red[c8 + 24 * ss][j];
        float* dst = ssq + (((size_t)(sel * 2 + b)) * 64 + ch) * C_ + c8 * 8;
#pragma unroll
        for (int j = 0; j < 8; j++) dst[j] = o[j];
    }
}

// ---------------- S partials: per (b,hd,chunk) 48x48 over 1024 positions ----------------
__global__ __launch_bounds__(256) void k_qk(const bf16* __restrict__ q,
                                            const bf16* __restrict__ k,
                                            float* __restrict__ Spart) {
    __shared__ float qs[64][49];
    __shared__ float ks[64][49];
    int t = threadIdx.x;
    int ch = blockIdx.x, hd = blockIdx.y, b = blockIdx.z;
    int i0 = (t >> 4) * 3, j0 = (t & 15) * 3;
    float acc[3][3];
#pragma unroll
    for (int a = 0; a < 3; a++)
#pragma unroll
        for (int c = 0; c < 3; c++) acc[a][c] = 0.f;

    for (int sub = 0; sub < 16; sub++) {
        size_t rbase = ((size_t)b * HW_ + ch * 1024 + sub * 64) * C_ + hd * 48;
        for (int i = t; i < 64 * 6; i += 256) {
            int row = i / 6, oc = i % 6;
            uint4 v = *(const uint4*)(q + rbase + (size_t)row * C_ + oc * 8);
            const bf16* pv = (const bf16*)&v;
#pragma unroll
            for (int j = 0; j < 8; j++) qs[row][oc * 8 + j] = fb(pv[j]);
            uint4 v2 = *(const uint4*)(k + rbase + (size_t)row * C_ + oc * 8);
            const bf16* pv2 = (const bf16*)&v2;
#pragma unroll
            for (int j = 0; j < 8; j++) ks[row][oc * 8 + j] = fb(pv2[j]);
        }
        __syncthreads();
        for (int p = 0; p < 64; p++) {
            float a0 = qs[p][i0], a1 = qs[p][i0 + 1], a2 = qs[p][i0 + 2];
            float b0 = ks[p][j0], b1 = ks[p][j0 + 1], b2 = ks[p][j0 + 2];
            acc[0][0] += a0 * b0; acc[0][1] += a0 * b1; acc[0][2] += a0 * b2;
            acc[1][0] += a1 * b0; acc[1][1] += a1 * b1; acc[1][2] += a1 * b2;
            acc[2][0] += a2 * b0; acc[2][1] += a2 * b1; acc[2][2] += a2 * b2;
        }
        __syncthreads();
    }
    float* dst = Spart + (((size_t)(b * 4 + hd)) * 16 + ch) * 2304;
#pragma unroll
    for (int a = 0; a < 3; a++)
#pragma unroll
        for (int c = 0; c < 3; c++) dst[(i0 + a) * 48 + (j0 + c)] = acc[a][c];
}

// ---------------- softmax with fused invq/invk reduction from ssq partials -------------
__global__ void k_softmax(const float* __restrict__ Spart, const float* __restrict__ ssq,
                          const float* __restrict__ temp, float* __restrict__ attn) {
    __shared__ float invk_s[48];
    int t = threadIdx.x;
    int hd = blockIdx.x, b = blockIdx.y;
    float qi = 0.f;
    if (t < 48) {
        int c = hd * 48 + t;
        float sq = 0.f, sk = 0.f;
        for (int ch = 0; ch < 64; ch++) {
            sq += ssq[((size_t)(b) * 64 + ch) * C_ + c];       // sel=0
            sk += ssq[((size_t)(2 + b) * 64 + ch) * C_ + c];   // sel=1
        }
        qi = 1.f / fmaxf(sqrtf(sq), 1e-12f);
        invk_s[t] = 1.f / fmaxf(sqrtf(sk), 1e-12f);
    }
    __syncthreads();
    if (t >= 48) return;
    const float* base = Spart + ((size_t)(b * 4 + hd)) * 16 * 2304;
    float tp = temp[hd];
    float row[48];
    float mx = -1e30f;
    for (int j = 0; j < 48; j++) {
        float s = 0.f;
        for (int ch = 0; ch < 16; ch++) s += base[ch * 2304 + t * 48 + j];
        s *= qi * invk_s[j] * tp;
        row[j] = s;
        mx = fmaxf(mx, s);
    }
    float sum = 0.f;
    for (int j = 0; j < 48; j++) { row[j] = expf(row[j] - mx); sum += row[j]; }
    float is = 1.f / sum;
    for (int j = 0; j < 48; j++)
        attn[(((size_t)(b * 4 + hd)) * 48 + t) * 48 + j] = row[j] * is;
}

// ---------------- out = attn @ v  (per position, per head) ----------------
__global__ __launch_bounds__(256) void k_av(const float* __restrict__ attn,
                                            const bf16* __restrict__ v,
                                            bf16* __restrict__ out) {
    __shared__ float As[4 * 48 * 48];
    int t = threadIdx.x;
    int b = blockIdx.y;
    for (int i = t; i < 9216; i += 256) As[i] = attn[(size_t)b * 9216 + i];
    __syncthreads();
    int p = blockIdx.x * 64 + (t >> 2);
    int hd = t & 3;
    size_t row = (size_t)b * HW_ + p;
    const float* am = As + hd * 2304;
    float acc[48];
#pragma unroll
    for (int i = 0; i < 48; i++) acc[i] = 0.f;
#pragma unroll
    for (int jo = 0; jo < 6; jo++) {
        uint4 vv = *(const uint4*)(v + row * C_ + hd * 48 + jo * 8);
        const bf16* pv = (const bf16*)&vv;
#pragma unroll
        for (int jj = 0; jj < 8; jj++) {
            float vj = fb(pv[jj]);
            int j = jo * 8 + jj;
#pragma unroll
            for (int i = 0; i < 48; i++) acc[i] += am[i * 48 + j] * vj;
        }
    }
#pragma unroll
    for (int io = 0; io < 6; io++) {
        union { bf16 h[8]; uint4 u; } ov;
#pragma unroll
        for (int jj = 0; jj < 8; jj++) ov.h[jj] = tob(acc[io * 8 + jj]);
        *(uint4*)(out + row * C_ + hd * 48 + io * 8) = ov.u;
    }
}

// =====================================================================================
extern "C" void kernel_launch(void* const* d_in, const int* in_sizes, int n_in,
                              void* d_out, int out_size, void* d_ws, size_t ws_size,
                              hipStream_t stream) {
    const float* x     = (const float*)d_in[0];
    const float* illum = (const float*)d_in[1];
    const float* ln1w  = (const float*)d_in[2];
    const float* ln1b  = (const float*)d_in[3];
    const float* lnLw  = (const float*)d_in[4];
    const float* lnLb  = (const float*)d_in[5];
    const float* ln2w  = (const float*)d_in[6];
    const float* ln2b  = (const float*)d_in[7];
    const float* qw    = (const float*)d_in[8];
    const float* qdww  = (const float*)d_in[9];
    const float* kvw   = (const float*)d_in[10];
    const float* kvdww = (const float*)d_in[11];
    const float* temp  = (const float*)d_in[12];
    const float* projw = (const float*)d_in[13];
    const float* pinw  = (const float*)d_in[14];
    const float* dww   = (const float*)d_in[15];
    const float* poutw = (const float*)d_in[16];

    char* ws = (char*)d_ws;
    bf16*  Wq1   = (bf16*)(ws + 0);
    bf16*  Wkv   = (bf16*)(ws + 73728);
    bf16*  Wqdw  = (bf16*)(ws + 221184);
    bf16*  Wproj = (bf16*)(ws + 884736);
    bf16*  Wpin  = (bf16*)(ws + 958464);
    bf16*  Wdw   = (bf16*)(ws + 1155072);
    bf16*  Wpout = (bf16*)(ws + 5873664);
    float* Spart = (float*)(ws + 6070272);
    float* attn  = (float*)(ws + 7249920);
    float* ssq   = (float*)(ws + 7323648);
    char*  zpage = (char*)(ws + 7523328);
    const size_t A0 = 7527424, u = 12582912;
    bf16* xn    = (bf16*)(ws + A0 + 0 * u);
    bf16* iln   = (bf16*)(ws + A0 + 1 * u);
    bf16* qtmp  = (bf16*)(ws + A0 + 2 * u);
    bf16* qb    = (bf16*)(ws + A0 + 1 * u);
    bf16* kvtmp = (bf16*)(ws + A0 + 2 * u);
    bf16* kb    = (bf16*)(ws + A0 + 0 * u);
    bf16* vb    = (bf16*)(ws + A0 + 4 * u);
    bf16* outa  = (bf16*)(ws + A0 + 2 * u);
    bf16* x2    = (bf16*)(ws + A0 + 0 * u);
    bf16* xn2   = (bf16*)(ws + A0 + 3 * u);
    bf16* fbuf  = (bf16*)(ws + A0 + 4 * u);
    bf16* gbuf  = (bf16*)(ws + A0 + 1 * u);

    // 0) all weight repacks + zero page in one launch
    k_repack_all<<<11857, 256, 0, stream>>>(qw, kvw, projw, pinw, poutw, qdww, dww,
                                            Wq1, Wkv, Wproj, Wpin, Wpout, Wqdw, Wdw, zpage);

    // 1) both NCHW LayerNorms fused
    k_ln_nchw<<<dim3(512, 2), 256, 0, stream>>>(x, illum, ln1w, ln1b, lnLw, lnLb, xn, iln);

    // 2) q = 1x1(iln) ; full 3x3 -> qb
    k_gemm1x1<96, 1><<<dim3(256, 2), 256, 0, stream>>>(iln, Wq1, 192, 192, qtmp, nullptr);
    k_gemm3x3<96, 0><<<dim3(256, 2), 256, 0, stream>>>(qtmp, Wqdw, 192, 192, qb, zpage);

    // 3) kv = 1x1(xn) ; depthwise 3x3 -> kb, vb
    k_gemm1x1<128, 1><<<dim3(256, 3), 256, 0, stream>>>(xn, Wkv, 192, 384, kvtmp, nullptr);
    k_dwconv2<<<dim3(256, 2), 192, 0, stream>>>(kvtmp, kvdww, kb, vb);

    // 4) attention
    k_ssqpart<<<dim3(64, 2, 2), 192, 0, stream>>>(qb, kb, ssq);
    k_qk<<<dim3(16, 4, 2), 256, 0, stream>>>(qb, kb, Spart);
    k_softmax<<<dim3(4, 2), 64, 0, stream>>>(Spart, ssq, temp, attn);
    k_av<<<dim3(256, 2), 256, 0, stream>>>(attn, vb, outa);

    // 5) x2 = x + proj(out)
    k_gemm1x1<96, 2><<<dim3(256, 2), 256, 0, stream>>>(outa, Wproj, 192, 192, x2, x);

    // 6) FFN
    k_ln_pc<<<512, 256, 0, stream>>>(x2, ln2w, ln2b, xn2);
    k_gemm1x1<128, 1><<<dim3(256, 4), 256, 0, stream>>>(xn2, Wpin, 192, 512, fbuf, nullptr);
    k_gemm3x3<128, 1><<<dim3(256, 4), 256, 0, stream>>>(fbuf, Wdw, 512, 512, gbuf, zpage);
    k_gemm1x1<96, 3><<<dim3(256, 2), 256, 0, stream>>>(gbuf, Wpout, 512, 192, d_out, x2);
}

// Round 8
// 406.621 us; speedup vs baseline: 1.4263x; 1.2127x over previous
//
#include <hip/hip_runtime.h>
#include <hip/hip_bf16.h>

typedef __hip_bfloat16 bf16;
typedef __attribute__((ext_vector_type(8))) short bf16x8v;
typedef __attribute__((ext_vector_type(4))) float f32x4;

namespace {
constexpr int B_  = 2;
constexpr int C_  = 192;
constexpr int HW_ = 128 * 128;   // 16384
constexpr int C2_ = 384;
}

static __device__ __forceinline__ float fb(bf16 v) { return __bfloat162float(v); }
static __device__ __forceinline__ bf16 tob(float v) { return __float2bfloat16(v); }

typedef __attribute__((address_space(1))) const char GChar;
typedef __attribute__((address_space(3))) char LChar;
// async global->LDS, 16B per lane; LDS dest = wave-uniform base + lane*16
static __device__ __forceinline__ void gl16(const void* g, void* l) {
    __builtin_amdgcn_global_load_lds((GChar*)g, (LChar*)l, 16, 0, 0);
}
// swizzled LDS fragment read: 128B rows, 16B slots, slot ^= row&7
static __device__ __forceinline__ bf16x8v lread(const bf16* base, int row, int slot) {
    const char* p = (const char*)base + (size_t)row * 128 + ((size_t)((slot ^ (row & 7))) << 4);
    return *(const bf16x8v*)p;
}

// ---------------- fused weight repack + zero page (one kernel, range dispatch) ---------
static __device__ __forceinline__ void rp1(const float* W, bf16* Wr, int blk, int t,
                                           int N, int K, int Npad, int Kpad) {
    int i = blk * 256 + t;
    if (i >= Npad * Kpad) return;
    int n = i / Kpad, k = i % Kpad;
    float v = (n < N && k < K) ? W[n * K + k] : 0.f;
    Wr[i] = tob(v);
}
// one thread per (n,k): read 9 contiguous taps, scatter to 9 planes (all coalesced)
static __device__ __forceinline__ void rp3(const float* W, bf16* Wr, int blk, int t,
                                           int N, int K, int Npad, int Kpad) {
    int i = blk * 256 + t;
    int NK = Npad * Kpad;
    if (i >= NK) return;
    int n = i / Kpad, k = i % Kpad;
    if (n < N && k < K) {
        const float* src = W + ((size_t)(n * K + k)) * 9;
#pragma unroll
        for (int q = 0; q < 9; q++) Wr[(size_t)q * NK + i] = tob(src[q]);
    } else {
#pragma unroll
        for (int q = 0; q < 9; q++) Wr[(size_t)q * NK + i] = tob(0.f);
    }
}
__global__ __launch_bounds__(256) void k_repack_all(
    const float* __restrict__ qw, const float* __restrict__ kvw,
    const float* __restrict__ projw, const float* __restrict__ pinw,
    const float* __restrict__ poutw, const float* __restrict__ qdww,
    const float* __restrict__ dww,
    bf16* __restrict__ Wq1, bf16* __restrict__ Wkv, bf16* __restrict__ Wproj,
    bf16* __restrict__ Wpin, bf16* __restrict__ Wpout, bf16* __restrict__ Wqdw,
    bf16* __restrict__ Wdw, char* __restrict__ zpage) {
    int blk = blockIdx.x, t = threadIdx.x;
    if (blk < 144)        rp1(qw,    Wq1,   blk,        t, 192, 192, 192, 192);
    else if (blk < 432)   rp1(kvw,   Wkv,   blk - 144,  t, 384, 192, 384, 192);
    else if (blk < 576)   rp1(projw, Wproj, blk - 432,  t, 192, 192, 192, 192);
    else if (blk < 960)   rp1(pinw,  Wpin,  blk - 576,  t, 510, 192, 512, 192);
    else if (blk < 1344)  rp1(poutw, Wpout, blk - 960,  t, 192, 510, 192, 512);
    else if (blk < 1488)  rp3(qdww,  Wqdw,  blk - 1344, t, 192, 192, 192, 192);
    else if (blk < 2512)  rp3(dww,   Wdw,   blk - 1488, t, 510, 510, 512, 512);
    else ((uint4*)zpage)[t] = make_uint4(0u, 0u, 0u, 0u);
}

// ---------------- LayerNorm: NCHW fp32 -> [p][c] bf16 (fused pair via grid.y) ----------
__global__ __launch_bounds__(256) void k_ln_nchw(const float* __restrict__ X0,
                                                 const float* __restrict__ X1,
                                                 const float* __restrict__ w0,
                                                 const float* __restrict__ b0,
                                                 const float* __restrict__ w1,
                                                 const float* __restrict__ b1,
                                                 bf16* __restrict__ out0,
                                                 bf16* __restrict__ out1) {
    const float* X = blockIdx.y ? X1 : X0;
    const float* w = blockIdx.y ? w1 : w0;
    const float* bb = blockIdx.y ? b1 : b0;
    bf16* out = blockIdx.y ? out1 : out0;
    __shared__ float lds[64][C_ + 1];
    int t = threadIdx.x;
    int p0 = blockIdx.x * 64;
    int b = p0 / HW_, pi0 = p0 % HW_;
    for (int i = t; i < 64 * C_; i += 256) {
        int c = i >> 6, pp = i & 63;
        lds[pp][c] = X[((size_t)(b * C_ + c)) * HW_ + pi0 + pp];
    }
    __syncthreads();
    int pp = t >> 2, qq = t & 3;
    float s = 0.f, s2 = 0.f;
    for (int c = qq * 48; c < qq * 48 + 48; c++) { float v = lds[pp][c]; s += v; s2 += v * v; }
    s  += __shfl_xor(s, 1);  s  += __shfl_xor(s, 2);
    s2 += __shfl_xor(s2, 1); s2 += __shfl_xor(s2, 2);
    float mu = s / C_;
    float rstd = rsqrtf(s2 / C_ - mu * mu + 1e-5f);
    size_t ob = ((size_t)(p0 + pp)) * C_;
    for (int c = qq * 48; c < qq * 48 + 48; c++)
        out[ob + c] = tob((lds[pp][c] - mu) * rstd * w[c] + bb[c]);
}

// LayerNorm from [p][c] bf16 -> [p][c] bf16
__global__ __launch_bounds__(256) void k_ln_pc(const bf16* __restrict__ X2,
                                               const float* __restrict__ w,
                                               const float* __restrict__ bb,
                                               bf16* __restrict__ out) {
    int t = threadIdx.x;
    int p = blockIdx.x * 64 + (t >> 2), qq = t & 3;
    const bf16* row = X2 + (size_t)p * C_;
    float s = 0.f, s2 = 0.f;
    for (int c = qq * 48; c < qq * 48 + 48; c++) { float v = fb(row[c]); s += v; s2 += v * v; }
    s  += __shfl_xor(s, 1);  s  += __shfl_xor(s, 2);
    s2 += __shfl_xor(s2, 1); s2 += __shfl_xor(s2, 2);
    float mu = s / C_;
    float rstd = rsqrtf(s2 / C_ - mu * mu + 1e-5f);
    bf16* orow = out + (size_t)p * C_;
    for (int c = qq * 48; c < qq * 48 + 48; c++)
        orow[c] = tob((fb(row[c]) - mu) * rstd * w[c] + bb[c]);
}

// ---------------- 1x1 conv GEMM (global_load_lds + swizzle), BK=64 ----------------
// EPI: 1 = plain bf16 [p][Cout]
//      2 = +resid(NCHW f32)  -> bf16 [p][C_]
//      3 = +resid(bf16 [p][C_]) -> f32 NCHW
// wbstride: per-batch weight stride in elements (0 for shared weights)
template <int BN, int EPI>
__global__ __launch_bounds__(256) void k_gemm1x1(const bf16* __restrict__ A,
                                                 const bf16* __restrict__ Wr,
                                                 const int K, const int Cout,
                                                 void* __restrict__ outp,
                                                 const void* __restrict__ resid,
                                                 const int wbstride) {
    constexpr int WN = BN / 2, FN = WN / 16, BIT = BN / 32;
    __shared__ __align__(16) bf16 As[128 * 64];
    __shared__ __align__(16) bf16 Bs[BN * 64];
    const int t = threadIdx.x;
    const int mt = blockIdx.x;
    const int n0 = blockIdx.y * BN;
    const int b = mt >> 7, y = mt & 127;
    const int w = t >> 6, lane = t & 63;
    const int wm = w >> 1, wn = w & 1;
    const int g = lane >> 4, r = lane & 15;
    const int ldw = t - lane;  // w*64

    f32x4 acc[4][FN];
#pragma unroll
    for (int i = 0; i < 4; i++)
#pragma unroll
        for (int j = 0; j < FN; j++) acc[i][j] = {0.f, 0.f, 0.f, 0.f};

    const bf16* Abase = A + (size_t)mt * 128 * K;
    const bf16* Wbase = Wr + (size_t)b * wbstride;

    for (int c0 = 0; c0 < K; c0 += 64) {
#pragma unroll
        for (int it = 0; it < 4; it++) {
            int idx = it * 256 + t;
            int row = idx >> 3, sl = idx & 7;
            const char* gp = (const char*)(Abase + (size_t)row * K + c0) + ((sl ^ (row & 7)) << 4);
            gl16(gp, (char*)As + (size_t)(it * 256 + ldw) * 16);
        }
#pragma unroll
        for (int it = 0; it < BIT; it++) {
            int idx = it * 256 + t;
            int row = idx >> 3, sl = idx & 7;
            const char* gp = (const char*)(Wbase + (size_t)(n0 + row) * K + c0) + ((sl ^ (row & 7)) << 4);
            gl16(gp, (char*)Bs + (size_t)(it * 256 + ldw) * 16);
        }
        __syncthreads();
#pragma unroll
        for (int ks = 0; ks < 2; ks++) {
            bf16x8v af[4], bv[FN];
#pragma unroll
            for (int fm = 0; fm < 4; fm++)
                af[fm] = lread(As, wm * 64 + fm * 16 + r, ks * 4 + g);
#pragma unroll
            for (int fn = 0; fn < FN; fn++)
                bv[fn] = lread(Bs, wn * WN + fn * 16 + r, ks * 4 + g);
#pragma unroll
            for (int fm = 0; fm < 4; fm++)
#pragma unroll
                for (int fn = 0; fn < FN; fn++)
                    acc[fm][fn] = __builtin_amdgcn_mfma_f32_16x16x32_bf16(af[fm], bv[fn], acc[fm][fn], 0, 0, 0);
        }
        __syncthreads();
    }

#pragma unroll
    for (int fm = 0; fm < 4; fm++)
#pragma unroll
        for (int fn = 0; fn < FN; fn++)
#pragma unroll
            for (int reg = 0; reg < 4; reg++) {
                int xl = wm * 64 + fm * 16 + g * 4 + reg;
                int co = n0 + wn * WN + fn * 16 + r;
                float v = acc[fm][fn][reg];
                if constexpr (EPI == 1) {
                    ((bf16*)outp)[((size_t)mt * 128 + xl) * Cout + co] = tob(v);
                } else if constexpr (EPI == 2) {
                    v += ((const float*)resid)[((size_t)(b * C_ + co)) * HW_ + y * 128 + xl];
                    ((bf16*)outp)[((size_t)mt * 128 + xl) * C_ + co] = tob(v);
                } else {
                    v += fb(((const bf16*)resid)[((size_t)mt * 128 + xl) * C_ + co]);
                    ((float*)outp)[((size_t)(b * C_ + co)) * HW_ + y * 128 + xl] = v;
                }
            }
}

// ---------------- 3x3 full conv implicit GEMM, simple 2-barrier + XCD mt-swizzle ------
template <int BN, int EPI>
__global__ __launch_bounds__(256) void k_gemm3x3(const bf16* __restrict__ A,
                                                 const bf16* __restrict__ Wr,
                                                 const int Cin, const int Cout,
                                                 bf16* __restrict__ outp,
                                                 const char* __restrict__ zpage) {
    constexpr int WN = BN / 2, FN = WN / 16, BIT = BN / 32;
    __shared__ __align__(16) bf16 As[160 * 64];
    __shared__ __align__(16) bf16 Bs[BN * 64];
    const int t = threadIdx.x;
    const int mtRaw = blockIdx.x;
    const int mt = ((mtRaw & 7) << 5) | (mtRaw >> 3);   // XCD-contiguous rows
    const int n0 = blockIdx.y * BN;
    const int b = mt >> 7, y = mt & 127;
    const int w = t >> 6, lane = t & 63;
    const int wm = w >> 1, wn = w & 1;
    const int g = lane >> 4, r = lane & 15;
    const int ldw = t - lane;

    f32x4 acc[4][FN];
#pragma unroll
    for (int i = 0; i < 4; i++)
#pragma unroll
        for (int j = 0; j < FN; j++) acc[i][j] = {0.f, 0.f, 0.f, 0.f};

    for (int ky = 0; ky < 3; ky++) {
        const int yy = y + ky - 1;
        if (yy < 0 || yy > 127) continue;   // block-uniform
        const bf16* Ab = A + ((size_t)b * HW_ + (size_t)yy * 128) * Cin;
        for (int c0 = 0; c0 < Cin; c0 += 64) {
            for (int kx = 0; kx < 3; kx++) {
                if (kx == 0) {
#pragma unroll
                    for (int it = 0; it < 5; it++) {
                        int idx = it * 256 + t;
                        int row = idx >> 3, sl = idx & 7;
                        int so = (sl ^ (row & 7)) << 4;
                        const char* gp = (row >= 1 && row <= 128)
                            ? (const char*)(Ab + (size_t)(row - 1) * Cin + c0) + so
                            : zpage + so;
                        gl16(gp, (char*)As + (size_t)(it * 256 + ldw) * 16);
                    }
                }
                const bf16* Wb = Wr + (size_t)(ky * 3 + kx) * Cout * Cin;
#pragma unroll
                for (int it = 0; it < BIT; it++) {
                    int idx = it * 256 + t;
                    int row = idx >> 3, sl = idx & 7;
                    const char* gp = (const char*)(Wb + (size_t)(n0 + row) * Cin + c0) + ((sl ^ (row & 7)) << 4);
                    gl16(gp, (char*)Bs + (size_t)(it * 256 + ldw) * 16);
                }
                __syncthreads();
#pragma unroll
                for (int ks = 0; ks < 2; ks++) {
                    bf16x8v af[4], bv[FN];
#pragma unroll
                    for (int fm = 0; fm < 4; fm++)
                        af[fm] = lread(As, wm * 64 + fm * 16 + r + kx, ks * 4 + g);
#pragma unroll
                    for (int fn = 0; fn < FN; fn++)
                        bv[fn] = lread(Bs, wn * WN + fn * 16 + r, ks * 4 + g);
#pragma unroll
                    for (int fm = 0; fm < 4; fm++)
#pragma unroll
                        for (int fn = 0; fn < FN; fn++)
                            acc[fm][fn] = __builtin_amdgcn_mfma_f32_16x16x32_bf16(af[fm], bv[fn], acc[fm][fn], 0, 0, 0);
                }
                __syncthreads();
            }
        }
    }
#pragma unroll
    for (int fm = 0; fm < 4; fm++)
#pragma unroll
        for (int fn = 0; fn < FN; fn++)
#pragma unroll
            for (int reg = 0; reg < 4; reg++) {
                int xl = wm * 64 + fm * 16 + g * 4 + reg;
                int co = n0 + wn * WN + fn * 16 + r;
                float v = acc[fm][fn][reg];
                if constexpr (EPI == 1) v = 0.5f * v * (1.0f + erff(v * 0.70710678118654752f));
                outp[((size_t)mt * 128 + xl) * Cout + co] = tob(v);
            }
}

// ---------------- depthwise 3x3: weights in LDS->VGPR, 16 x-positions per thread -------
__global__ __launch_bounds__(192) void k_dwconv2(const bf16* __restrict__ kv,
                                                 const float* __restrict__ wdw,
                                                 bf16* __restrict__ kout,
                                                 bf16* __restrict__ vout) {
    __shared__ float wlds[1728];
    const int t = threadIdx.x;
    const int row = blockIdx.x;
    const int z = blockIdx.y;
    const int b = row >> 7, y = row & 127;
    for (int i = t; i < 432; i += 192)
        ((float4*)wlds)[i] = ((const float4*)(wdw + (size_t)z * 1728))[i];
    __syncthreads();
    const int c8h = t % 24, xg = t / 24;
    const int cbase = z * C_ + c8h * 8;
    float wreg[9][8];
#pragma unroll
    for (int tap = 0; tap < 9; tap++)
#pragma unroll
        for (int j = 0; j < 8; j++) wreg[tap][j] = wlds[(c8h * 8 + j) * 9 + tap];

    bf16* outb = (z == 0 ? kout : vout) + (size_t)(b * HW_ + y * 128) * C_ + c8h * 8;
    const uint4 zero4 = make_uint4(0u, 0u, 0u, 0u);
    for (int i = 0; i < 16; i++) {
        int x = xg + 8 * i;
        float acc[8];
#pragma unroll
        for (int j = 0; j < 8; j++) acc[j] = 0.f;
#pragma unroll
        for (int ky = 0; ky < 3; ky++) {
            int yy = y + ky - 1;
            if (yy < 0 || yy > 127) continue;
            const bf16* rb = kv + ((size_t)b * HW_ + (size_t)yy * 128) * C2_ + cbase;
#pragma unroll
            for (int kx = 0; kx < 3; kx++) {
                int xx = x + kx - 1;
                uint4 vv = (xx >= 0 && xx <= 127) ? *(const uint4*)(rb + (size_t)xx * C2_) : zero4;
                const bf16* pv = (const bf16*)&vv;
#pragma unroll
                for (int j = 0; j < 8; j++)
                    acc[j] += fb(pv[j]) * wreg[ky * 3 + kx][j];
            }
        }
        union { bf16 h[8]; uint4 u; } ov;
#pragma unroll
        for (int j = 0; j < 8; j++) ov.h[j] = tob(acc[j]);
        *(uint4*)(outb + (size_t)x * C_) = ov.u;
    }
}

// ---------------- deterministic per-(sel,b,c) sum-of-squares partials (vectorized) -----
__global__ __launch_bounds__(192) void k_ssqpart(const bf16* __restrict__ q,
                                                 const bf16* __restrict__ k,
                                                 float* __restrict__ ssq) {
    __shared__ float red[192][8];
    int t = threadIdx.x;
    int c8 = t % 24, slot = t / 24;
    int ch = blockIdx.x, b = blockIdx.y, sel = blockIdx.z;
    const bf16* src = (sel ? k : q) + ((size_t)b * HW_ + ch * 256) * C_ + c8 * 8;
    float s[8];
#pragma unroll
    for (int j = 0; j < 8; j++) s[j] = 0.f;
    for (int i = slot; i < 256; i += 8) {
        uint4 v = *(const uint4*)(src + (size_t)i * C_);
        const bf16* pv = (const bf16*)&v;
#pragma unroll
        for (int j = 0; j < 8; j++) { float x = fb(pv[j]); s[j] += x * x; }
    }
#pragma unroll
    for (int j = 0; j < 8; j++) red[t][j] = s[j];
    __syncthreads();
    if (slot == 0) {
        float o[8];
#pragma unroll
        for (int j = 0; j < 8; j++) o[j] = 0.f;
        for (int ss = 0; ss < 8; ss++)
#pragma unroll
            for (int j = 0; j < 8; j++) o[j] += red[c8 + 24 * ss][j];
        float* dst = ssq + (((size_t)(sel * 2 + b)) * 64 + ch) * C_ + c8 * 8;
#pragma unroll
        for (int j = 0; j < 8; j++) dst[j] = o[j];
    }
}

// ---------------- S partials: per (b,hd,chunk) 48x48 over 256 positions (64 chunks) ----
__global__ __launch_bounds__(256) void k_qk(const bf16* __restrict__ q,
                                            const bf16* __restrict__ k,
                                            float* __restrict__ Spart) {
    __shared__ float qs[64][49];
    __shared__ float ks[64][49];
    int t = threadIdx.x;
    int ch = blockIdx.x, hd = blockIdx.y, b = blockIdx.z;
    int i0 = (t >> 4) * 3, j0 = (t & 15) * 3;
    float acc[3][3];
#pragma unroll
    for (int a = 0; a < 3; a++)
#pragma unroll
        for (int c = 0; c < 3; c++) acc[a][c] = 0.f;

    for (int sub = 0; sub < 4; sub++) {
        size_t rbase = ((size_t)b * HW_ + ch * 256 + sub * 64) * C_ + hd * 48;
        for (int i = t; i < 64 * 6; i += 256) {
            int row = i / 6, oc = i % 6;
            uint4 v = *(const uint4*)(q + rbase + (size_t)row * C_ + oc * 8);
            const bf16* pv = (const bf16*)&v;
#pragma unroll
            for (int j = 0; j < 8; j++) qs[row][oc * 8 + j] = fb(pv[j]);
            uint4 v2 = *(const uint4*)(k + rbase + (size_t)row * C_ + oc * 8);
            const bf16* pv2 = (const bf16*)&v2;
#pragma unroll
            for (int j = 0; j < 8; j++) ks[row][oc * 8 + j] = fb(pv2[j]);
        }
        __syncthreads();
        for (int p = 0; p < 64; p++) {
            float a0 = qs[p][i0], a1 = qs[p][i0 + 1], a2 = qs[p][i0 + 2];
            float b0 = ks[p][j0], b1 = ks[p][j0 + 1], b2 = ks[p][j0 + 2];
            acc[0][0] += a0 * b0; acc[0][1] += a0 * b1; acc[0][2] += a0 * b2;
            acc[1][0] += a1 * b0; acc[1][1] += a1 * b1; acc[1][2] += a1 * b2;
            acc[2][0] += a2 * b0; acc[2][1] += a2 * b1; acc[2][2] += a2 * b2;
        }
        __syncthreads();
    }
    float* dst = Spart + (((size_t)(b * 4 + hd)) * 64 + ch) * 2304;
#pragma unroll
    for (int a = 0; a < 3; a++)
#pragma unroll
        for (int c = 0; c < 3; c++) dst[(i0 + a) * 48 + (j0 + c)] = acc[a][c];
}

// ---------------- softmax: reduce 64 chunks, fused inv-norms, emit block-diag bf16 W ---
__global__ __launch_bounds__(256) void k_softmax(const float* __restrict__ Spart,
                                                 const float* __restrict__ ssq,
                                                 const float* __restrict__ temp,
                                                 bf16* __restrict__ attnW) {
    __shared__ float S[2304];
    __shared__ float invk_s[48];
    int t = threadIdx.x;
    int hd = blockIdx.x, b = blockIdx.y;
    const float* base = Spart + ((size_t)(b * 4 + hd)) * 64 * 2304;
    for (int e = t; e < 2304; e += 256) {
        float s = 0.f;
        for (int ch = 0; ch < 64; ch++) s += base[(size_t)ch * 2304 + e];
        S[e] = s;
    }
    if (t < 48) {
        int c = hd * 48 + t;
        float sk = 0.f;
        for (int ch = 0; ch < 64; ch++) sk += ssq[((size_t)(2 + b) * 64 + ch) * C_ + c];
        invk_s[t] = 1.f / fmaxf(sqrtf(sk), 1e-12f);
    }
    __syncthreads();
    if (t >= 48) return;
    int c = hd * 48 + t;
    float sq = 0.f;
    for (int ch = 0; ch < 64; ch++) sq += ssq[((size_t)b * 64 + ch) * C_ + c];
    float qi = 1.f / fmaxf(sqrtf(sq), 1e-12f);
    float tp = temp[hd];
    float row[48];
    float mx = -1e30f;
    for (int j = 0; j < 48; j++) {
        float s = S[t * 48 + j] * qi * invk_s[j] * tp;
        row[j] = s;
        mx = fmaxf(mx, s);
    }
    float sum = 0.f;
    for (int j = 0; j < 48; j++) { row[j] = expf(row[j] - mx); sum += row[j]; }
    float is = 1.f / sum;
    // block-diagonal 192x192 weight row (co = hd*48+t): attn on diag block, zeros off
    bf16* wrow = attnW + ((size_t)b * 192 + hd * 48 + t) * 192;
    for (int blk4 = 0; blk4 < 4; blk4++)
        for (int j = 0; j < 48; j++)
            wrow[blk4 * 48 + j] = tob(blk4 == hd ? row[j] * is : 0.f);
}

// =====================================================================================
extern "C" void kernel_launch(void* const* d_in, const int* in_sizes, int n_in,
                              void* d_out, int out_size, void* d_ws, size_t ws_size,
                              hipStream_t stream) {
    const float* x     = (const float*)d_in[0];
    const float* illum = (const float*)d_in[1];
    const float* ln1w  = (const float*)d_in[2];
    const float* ln1b  = (const float*)d_in[3];
    const float* lnLw  = (const float*)d_in[4];
    const float* lnLb  = (const float*)d_in[5];
    const float* ln2w  = (const float*)d_in[6];
    const float* ln2b  = (const float*)d_in[7];
    const float* qw    = (const float*)d_in[8];
    const float* qdww  = (const float*)d_in[9];
    const float* kvw   = (const float*)d_in[10];
    const float* kvdww = (const float*)d_in[11];
    const float* temp  = (const float*)d_in[12];
    const float* projw = (const float*)d_in[13];
    const float* pinw  = (const float*)d_in[14];
    const float* dww   = (const float*)d_in[15];
    const float* poutw = (const float*)d_in[16];

    char* ws = (char*)d_ws;
    bf16*  Wq1   = (bf16*)(ws + 0);
    bf16*  Wkv   = (bf16*)(ws + 73728);
    bf16*  Wqdw  = (bf16*)(ws + 221184);
    bf16*  Wproj = (bf16*)(ws + 884736);
    bf16*  Wpin  = (bf16*)(ws + 958464);
    bf16*  Wdw   = (bf16*)(ws + 1155072);
    bf16*  Wpout = (bf16*)(ws + 5873664);
    float* ssq   = (float*)(ws + 6070272);   //  196,608
    char*  zpage = (char*)(ws + 6266880);    //    4,096
    const size_t A0 = 6270976, u = 12582912;
    bf16* xn    = (bf16*)(ws + A0 + 0 * u);   // [LN1, kv-gemm]
    bf16* iln   = (bf16*)(ws + A0 + 1 * u);   // [LNL, q-1x1]
    bf16* qtmp  = (bf16*)(ws + A0 + 2 * u);   // [q-1x1, q-3x3]
    bf16* qb    = (bf16*)(ws + A0 + 1 * u);   // [q-3x3, qk]
    bf16* kvtmp = (bf16*)(ws + A0 + 2 * u);   // [kv-gemm, dwconv] slots 2-3
    bf16* kb    = (bf16*)(ws + A0 + 0 * u);   // [dwconv, qk]
    bf16* vb    = (bf16*)(ws + A0 + 4 * u);   // [dwconv, av-gemm]
    float* Spart = (float*)(ws + A0 + 3 * u);          // [qk, softmax] 4.7 MB (slot 3)
    bf16*  attnW = (bf16*)(ws + A0 + 3 * u + 4718592); // [softmax, av-gemm] 147 KB
    bf16* outa  = (bf16*)(ws + A0 + 2 * u);   // [av-gemm, proj]
    bf16* x2    = (bf16*)(ws + A0 + 0 * u);   // [proj, pout]
    bf16* xn2   = (bf16*)(ws + A0 + 3 * u);   // [LN2, pin]
    bf16* fbuf  = (bf16*)(ws + A0 + 4 * u);   // [pin, dw3x3] 33.5 MB
    bf16* gbuf  = (bf16*)(ws + A0 + 1 * u);   // [dw3x3, pout] 33.5 MB (slots 1-3)
    // total = A0 + 4u + 33,554,432 = 90,157,056 bytes (~86 MB)

    // 0) all weight repacks + zero page in one launch
    k_repack_all<<<2513, 256, 0, stream>>>(qw, kvw, projw, pinw, poutw, qdww, dww,
                                           Wq1, Wkv, Wproj, Wpin, Wpout, Wqdw, Wdw, zpage);

    // 1) both NCHW LayerNorms fused
    k_ln_nchw<<<dim3(512, 2), 256, 0, stream>>>(x, illum, ln1w, ln1b, lnLw, lnLb, xn, iln);

    // 2) q = 1x1(iln) ; full 3x3 -> qb
    k_gemm1x1<96, 1><<<dim3(256, 2), 256, 0, stream>>>(iln, Wq1, 192, 192, qtmp, nullptr, 0);
    k_gemm3x3<96, 0><<<dim3(256, 2), 256, 0, stream>>>(qtmp, Wqdw, 192, 192, qb, zpage);

    // 3) kv = 1x1(xn) ; depthwise 3x3 -> kb, vb
    k_gemm1x1<128, 1><<<dim3(256, 3), 256, 0, stream>>>(xn, Wkv, 192, 384, kvtmp, nullptr, 0);
    k_dwconv2<<<dim3(256, 2), 192, 0, stream>>>(kvtmp, kvdww, kb, vb);

    // 4) attention
    k_ssqpart<<<dim3(64, 2, 2), 192, 0, stream>>>(qb, kb, ssq);
    k_qk<<<dim3(64, 4, 2), 256, 0, stream>>>(qb, kb, Spart);
    k_softmax<<<dim3(4, 2), 256, 0, stream>>>(Spart, ssq, temp, attnW);
    // out = attn @ v as block-diag GEMM (per-batch weight)
    k_gemm1x1<96, 1><<<dim3(256, 2), 256, 0, stream>>>(vb, attnW, 192, 192, outa, nullptr, 36864);

    // 5) x2 = x + proj(out)
    k_gemm1x1<96, 2><<<dim3(256, 2), 256, 0, stream>>>(outa, Wproj, 192, 192, x2, x, 0);

    // 6) FFN
    k_ln_pc<<<512, 256, 0, stream>>>(x2, ln2w, ln2b, xn2);
    k_gemm1x1<128, 1><<<dim3(256, 4), 256, 0, stream>>>(xn2, Wpin, 192, 512, fbuf, nullptr, 0);
    k_gemm3x3<128, 1><<<dim3(256, 4), 256, 0, stream>>>(fbuf, Wdw, 512, 512, gbuf, zpage);
    k_gemm1x1<96, 3><<<dim3(256, 2), 256, 0, stream>>>(gbuf, Wpout, 512, 192, d_out, x2, 0);
}

// Round 9
// 380.781 us; speedup vs baseline: 1.5231x; 1.0679x over previous
//
#include <hip/hip_runtime.h>
#include <hip/hip_bf16.h>

typedef __hip_bfloat16 bf16;
typedef __attribute__((ext_vector_type(8))) short bf16x8v;
typedef __attribute__((ext_vector_type(4))) float f32x4;

namespace {
constexpr int B_  = 2;
constexpr int C_  = 192;
constexpr int HW_ = 128 * 128;   // 16384
constexpr int C2_ = 384;
}

static __device__ __forceinline__ float fb(bf16 v) { return __bfloat162float(v); }
static __device__ __forceinline__ bf16 tob(float v) { return __float2bfloat16(v); }

typedef __attribute__((address_space(1))) const char GChar;
typedef __attribute__((address_space(3))) char LChar;
// async global->LDS, 16B per lane; LDS dest = wave-uniform base + lane*16
static __device__ __forceinline__ void gl16(const void* g, void* l) {
    __builtin_amdgcn_global_load_lds((GChar*)g, (LChar*)l, 16, 0, 0);
}
// swizzled LDS fragment read: 128B rows, 16B slots, slot ^= row&7
static __device__ __forceinline__ bf16x8v lread(const bf16* base, int row, int slot) {
    const char* p = (const char*)base + (size_t)row * 128 + ((size_t)((slot ^ (row & 7))) << 4);
    return *(const bf16x8v*)p;
}

// ---------------- fused weight repack + zero page (one kernel, range dispatch) ---------
static __device__ __forceinline__ void rp1(const float* W, bf16* Wr, int blk, int t,
                                           int N, int K, int Npad, int Kpad) {
    int i = blk * 256 + t;
    if (i >= Npad * Kpad) return;
    int n = i / Kpad, k = i % Kpad;
    float v = (n < N && k < K) ? W[n * K + k] : 0.f;
    Wr[i] = tob(v);
}
// one thread per (n,k): read 9 contiguous taps, scatter to 9 planes (all coalesced)
static __device__ __forceinline__ void rp3(const float* W, bf16* Wr, int blk, int t,
                                           int N, int K, int Npad, int Kpad) {
    int i = blk * 256 + t;
    int NK = Npad * Kpad;
    if (i >= NK) return;
    int n = i / Kpad, k = i % Kpad;
    if (n < N && k < K) {
        const float* src = W + ((size_t)(n * K + k)) * 9;
#pragma unroll
        for (int q = 0; q < 9; q++) Wr[(size_t)q * NK + i] = tob(src[q]);
    } else {
#pragma unroll
        for (int q = 0; q < 9; q++) Wr[(size_t)q * NK + i] = tob(0.f);
    }
}
__global__ __launch_bounds__(256) void k_repack_all(
    const float* __restrict__ qw, const float* __restrict__ kvw,
    const float* __restrict__ projw, const float* __restrict__ pinw,
    const float* __restrict__ poutw, const float* __restrict__ qdww,
    const float* __restrict__ dww,
    bf16* __restrict__ Wq1, bf16* __restrict__ Wkv, bf16* __restrict__ Wproj,
    bf16* __restrict__ Wpin, bf16* __restrict__ Wpout, bf16* __restrict__ Wqdw,
    bf16* __restrict__ Wdw, char* __restrict__ zpage) {
    int blk = blockIdx.x, t = threadIdx.x;
    if (blk < 144)        rp1(qw,    Wq1,   blk,        t, 192, 192, 192, 192);
    else if (blk < 432)   rp1(kvw,   Wkv,   blk - 144,  t, 384, 192, 384, 192);
    else if (blk < 576)   rp1(projw, Wproj, blk - 432,  t, 192, 192, 192, 192);
    else if (blk < 960)   rp1(pinw,  Wpin,  blk - 576,  t, 510, 192, 512, 192);
    else if (blk < 1344)  rp1(poutw, Wpout, blk - 960,  t, 192, 510, 192, 512);
    else if (blk < 1488)  rp3(qdww,  Wqdw,  blk - 1344, t, 192, 192, 192, 192);
    else if (blk < 2512)  rp3(dww,   Wdw,   blk - 1488, t, 510, 510, 512, 512);
    else ((uint4*)zpage)[t] = make_uint4(0u, 0u, 0u, 0u);
}

// ---------------- LayerNorm: NCHW fp32 -> [p][c] bf16 (fused pair, vectorized) ---------
__global__ __launch_bounds__(256) void k_ln_nchw(const float* __restrict__ X0,
                                                 const float* __restrict__ X1,
                                                 const float* __restrict__ w0,
                                                 const float* __restrict__ b0,
                                                 const float* __restrict__ w1,
                                                 const float* __restrict__ b1,
                                                 bf16* __restrict__ out0,
                                                 bf16* __restrict__ out1) {
    const float* X = blockIdx.y ? X1 : X0;
    const float* w = blockIdx.y ? w1 : w0;
    const float* bb = blockIdx.y ? b1 : b0;
    bf16* out = blockIdx.y ? out1 : out0;
    __shared__ float lds[64][C_ + 1];
    int t = threadIdx.x;
    int p0 = blockIdx.x * 64;
    int b = p0 / HW_, pi0 = p0 % HW_;
    // float4 loads: i indexes (c, pp4); 16 float4 per channel row of 64
    for (int i = t; i < 64 * C_ / 4; i += 256) {
        int c = i >> 4, pp4 = (i & 15) << 2;
        float4 v = *(const float4*)(X + ((size_t)(b * C_ + c)) * HW_ + pi0 + pp4);
        lds[pp4 + 0][c] = v.x; lds[pp4 + 1][c] = v.y;
        lds[pp4 + 2][c] = v.z; lds[pp4 + 3][c] = v.w;
    }
    __syncthreads();
    int pp = t >> 2, qq = t & 3;
    float s = 0.f, s2 = 0.f;
    for (int c = qq * 48; c < qq * 48 + 48; c++) { float v = lds[pp][c]; s += v; s2 += v * v; }
    s  += __shfl_xor(s, 1);  s  += __shfl_xor(s, 2);
    s2 += __shfl_xor(s2, 1); s2 += __shfl_xor(s2, 2);
    float mu = s / C_;
    float rstd = rsqrtf(s2 / C_ - mu * mu + 1e-5f);
    bf16* ob = out + ((size_t)(p0 + pp)) * C_ + qq * 48;
#pragma unroll
    for (int j = 0; j < 6; j++) {
        union { bf16 h[8]; uint4 u; } ov;
#pragma unroll
        for (int e = 0; e < 8; e++) {
            int c = qq * 48 + j * 8 + e;
            ov.h[e] = tob((lds[pp][c] - mu) * rstd * w[c] + bb[c]);
        }
        *(uint4*)(ob + j * 8) = ov.u;
    }
}

// LayerNorm from [p][c] bf16 -> [p][c] bf16 (vectorized)
__global__ __launch_bounds__(256) void k_ln_pc(const bf16* __restrict__ X2,
                                               const float* __restrict__ w,
                                               const float* __restrict__ bb,
                                               bf16* __restrict__ out) {
    int t = threadIdx.x;
    int p = blockIdx.x * 64 + (t >> 2), qq = t & 3;
    const bf16* row = X2 + (size_t)p * C_ + qq * 48;
    uint4 u[6];
#pragma unroll
    for (int j = 0; j < 6; j++) u[j] = *(const uint4*)(row + j * 8);
    float s = 0.f, s2 = 0.f;
#pragma unroll
    for (int j = 0; j < 6; j++) {
        const bf16* pv = (const bf16*)&u[j];
#pragma unroll
        for (int e = 0; e < 8; e++) { float v = fb(pv[e]); s += v; s2 += v * v; }
    }
    s  += __shfl_xor(s, 1);  s  += __shfl_xor(s, 2);
    s2 += __shfl_xor(s2, 1); s2 += __shfl_xor(s2, 2);
    float mu = s / C_;
    float rstd = rsqrtf(s2 / C_ - mu * mu + 1e-5f);
    bf16* orow = out + (size_t)p * C_ + qq * 48;
#pragma unroll
    for (int j = 0; j < 6; j++) {
        const bf16* pv = (const bf16*)&u[j];
        union { bf16 h[8]; uint4 u4; } ov;
#pragma unroll
        for (int e = 0; e < 8; e++) {
            int c = qq * 48 + j * 8 + e;
            ov.h[e] = tob((fb(pv[e]) - mu) * rstd * w[c] + bb[c]);
        }
        *(uint4*)(orow + j * 8) = ov.u4;
    }
}

// ---------------- 1x1 conv GEMM (global_load_lds + swizzle), BK=64 ----------------
// EPI: 1 = plain bf16 [p][Cout]
//      2 = +resid(NCHW f32)  -> bf16 [p][C_]
//      3 = +resid(bf16 [p][C_]) -> f32 NCHW
// wbstride: per-batch weight stride in elements (0 for shared weights)
template <int BN, int EPI>
__global__ __launch_bounds__(256) void k_gemm1x1(const bf16* __restrict__ A,
                                                 const bf16* __restrict__ Wr,
                                                 const int K, const int Cout,
                                                 void* __restrict__ outp,
                                                 const void* __restrict__ resid,
                                                 const int wbstride) {
    constexpr int WN = BN / 2, FN = WN / 16, BIT = BN / 32;
    __shared__ __align__(16) bf16 As[128 * 64];
    __shared__ __align__(16) bf16 Bs[BN * 64];
    const int t = threadIdx.x;
    const int mt = blockIdx.x;
    const int n0 = blockIdx.y * BN;
    const int b = mt >> 7, y = mt & 127;
    const int w = t >> 6, lane = t & 63;
    const int wm = w >> 1, wn = w & 1;
    const int g = lane >> 4, r = lane & 15;
    const int ldw = t - lane;  // w*64

    f32x4 acc[4][FN];
#pragma unroll
    for (int i = 0; i < 4; i++)
#pragma unroll
        for (int j = 0; j < FN; j++) acc[i][j] = {0.f, 0.f, 0.f, 0.f};

    const bf16* Abase = A + (size_t)mt * 128 * K;
    const bf16* Wbase = Wr + (size_t)b * wbstride;

    for (int c0 = 0; c0 < K; c0 += 64) {
#pragma unroll
        for (int it = 0; it < 4; it++) {
            int idx = it * 256 + t;
            int row = idx >> 3, sl = idx & 7;
            const char* gp = (const char*)(Abase + (size_t)row * K + c0) + ((sl ^ (row & 7)) << 4);
            gl16(gp, (char*)As + (size_t)(it * 256 + ldw) * 16);
        }
#pragma unroll
        for (int it = 0; it < BIT; it++) {
            int idx = it * 256 + t;
            int row = idx >> 3, sl = idx & 7;
            const char* gp = (const char*)(Wbase + (size_t)(n0 + row) * K + c0) + ((sl ^ (row & 7)) << 4);
            gl16(gp, (char*)Bs + (size_t)(it * 256 + ldw) * 16);
        }
        __syncthreads();
#pragma unroll
        for (int ks = 0; ks < 2; ks++) {
            bf16x8v af[4], bv[FN];
#pragma unroll
            for (int fm = 0; fm < 4; fm++)
                af[fm] = lread(As, wm * 64 + fm * 16 + r, ks * 4 + g);
#pragma unroll
            for (int fn = 0; fn < FN; fn++)
                bv[fn] = lread(Bs, wn * WN + fn * 16 + r, ks * 4 + g);
#pragma unroll
            for (int fm = 0; fm < 4; fm++)
#pragma unroll
                for (int fn = 0; fn < FN; fn++)
                    acc[fm][fn] = __builtin_amdgcn_mfma_f32_16x16x32_bf16(af[fm], bv[fn], acc[fm][fn], 0, 0, 0);
        }
        __syncthreads();
    }

#pragma unroll
    for (int fm = 0; fm < 4; fm++)
#pragma unroll
        for (int fn = 0; fn < FN; fn++)
#pragma unroll
            for (int reg = 0; reg < 4; reg++) {
                int xl = wm * 64 + fm * 16 + g * 4 + reg;
                int co = n0 + wn * WN + fn * 16 + r;
                float v = acc[fm][fn][reg];
                if constexpr (EPI == 1) {
                    ((bf16*)outp)[((size_t)mt * 128 + xl) * Cout + co] = tob(v);
                } else if constexpr (EPI == 2) {
                    v += ((const float*)resid)[((size_t)(b * C_ + co)) * HW_ + y * 128 + xl];
                    ((bf16*)outp)[((size_t)mt * 128 + xl) * C_ + co] = tob(v);
                } else {
                    v += fb(((const bf16*)resid)[((size_t)mt * 128 + xl) * C_ + co]);
                    ((float*)outp)[((size_t)(b * C_ + co)) * HW_ + y * 128 + xl] = v;
                }
            }
}

// ---------------- 3x3 full conv implicit GEMM, simple 2-barrier + XCD mt-swizzle ------
template <int BN, int EPI>
__global__ __launch_bounds__(256) void k_gemm3x3(const bf16* __restrict__ A,
                                                 const bf16* __restrict__ Wr,
                                                 const int Cin, const int Cout,
                                                 bf16* __restrict__ outp,
                                                 const char* __restrict__ zpage) {
    constexpr int WN = BN / 2, FN = WN / 16, BIT = BN / 32;
    __shared__ __align__(16) bf16 As[160 * 64];
    __shared__ __align__(16) bf16 Bs[BN * 64];
    const int t = threadIdx.x;
    const int mtRaw = blockIdx.x;
    const int mt = ((mtRaw & 7) << 5) | (mtRaw >> 3);   // XCD-contiguous rows
    const int n0 = blockIdx.y * BN;
    const int b = mt >> 7, y = mt & 127;
    const int w = t >> 6, lane = t & 63;
    const int wm = w >> 1, wn = w & 1;
    const int g = lane >> 4, r = lane & 15;
    const int ldw = t - lane;

    f32x4 acc[4][FN];
#pragma unroll
    for (int i = 0; i < 4; i++)
#pragma unroll
        for (int j = 0; j < FN; j++) acc[i][j] = {0.f, 0.f, 0.f, 0.f};

    for (int ky = 0; ky < 3; ky++) {
        const int yy = y + ky - 1;
        if (yy < 0 || yy > 127) continue;   // block-uniform
        const bf16* Ab = A + ((size_t)b * HW_ + (size_t)yy * 128) * Cin;
        for (int c0 = 0; c0 < Cin; c0 += 64) {
            for (int kx = 0; kx < 3; kx++) {
                if (kx == 0) {
#pragma unroll
                    for (int it = 0; it < 5; it++) {
                        int idx = it * 256 + t;
                        int row = idx >> 3, sl = idx & 7;
                        int so = (sl ^ (row & 7)) << 4;
                        const char* gp = (row >= 1 && row <= 128)
                            ? (const char*)(Ab + (size_t)(row - 1) * Cin + c0) + so
                            : zpage + so;
                        gl16(gp, (char*)As + (size_t)(it * 256 + ldw) * 16);
                    }
                }
                const bf16* Wb = Wr + (size_t)(ky * 3 + kx) * Cout * Cin;
#pragma unroll
                for (int it = 0; it < BIT; it++) {
                    int idx = it * 256 + t;
                    int row = idx >> 3, sl = idx & 7;
                    const char* gp = (const char*)(Wb + (size_t)(n0 + row) * Cin + c0) + ((sl ^ (row & 7)) << 4);
                    gl16(gp, (char*)Bs + (size_t)(it * 256 + ldw) * 16);
                }
                __syncthreads();
#pragma unroll
                for (int ks = 0; ks < 2; ks++) {
                    bf16x8v af[4], bv[FN];
#pragma unroll
                    for (int fm = 0; fm < 4; fm++)
                        af[fm] = lread(As, wm * 64 + fm * 16 + r + kx, ks * 4 + g);
#pragma unroll
                    for (int fn = 0; fn < FN; fn++)
                        bv[fn] = lread(Bs, wn * WN + fn * 16 + r, ks * 4 + g);
#pragma unroll
                    for (int fm = 0; fm < 4; fm++)
#pragma unroll
                        for (int fn = 0; fn < FN; fn++)
                            acc[fm][fn] = __builtin_amdgcn_mfma_f32_16x16x32_bf16(af[fm], bv[fn], acc[fm][fn], 0, 0, 0);
                }
                __syncthreads();
            }
        }
    }
#pragma unroll
    for (int fm = 0; fm < 4; fm++)
#pragma unroll
        for (int fn = 0; fn < FN; fn++)
#pragma unroll
            for (int reg = 0; reg < 4; reg++) {
                int xl = wm * 64 + fm * 16 + g * 4 + reg;
                int co = n0 + wn * WN + fn * 16 + r;
                float v = acc[fm][fn][reg];
                if constexpr (EPI == 1) v = 0.5f * v * (1.0f + erff(v * 0.70710678118654752f));
                outp[((size_t)mt * 128 + xl) * Cout + co] = tob(v);
            }
}

// ---------------- depthwise 3x3: sliding-window cols, 16 contiguous x per thread -------
__global__ __launch_bounds__(192) void k_dwconv2(const bf16* __restrict__ kv,
                                                 const float* __restrict__ wdw,
                                                 bf16* __restrict__ kout,
                                                 bf16* __restrict__ vout) {
    __shared__ float wlds[1728];
    const int t = threadIdx.x;
    const int row = blockIdx.x;
    const int z = blockIdx.y;
    const int b = row >> 7, y = row & 127;
    for (int i = t; i < 432; i += 192)
        ((float4*)wlds)[i] = ((const float4*)(wdw + (size_t)z * 1728))[i];
    __syncthreads();
    const int c8h = t % 24, xg = t / 24;
    const int cbase = z * C_ + c8h * 8;
    float wreg[9][8];
#pragma unroll
    for (int tap = 0; tap < 9; tap++)
#pragma unroll
        for (int j = 0; j < 8; j++) wreg[tap][j] = wlds[(c8h * 8 + j) * 9 + tap];

    bf16* outb = (z == 0 ? kout : vout) + (size_t)(b * HW_ + y * 128) * C_ + c8h * 8;
    const uint4 zero4 = make_uint4(0u, 0u, 0u, 0u);
    const int x0 = xg * 16;
    bool vy[3]; const bf16* rowp[3];
#pragma unroll
    for (int ky = 0; ky < 3; ky++) {
        int yy = y + ky - 1;
        vy[ky] = (yy >= 0 && yy <= 127);
        int yyc = vy[ky] ? yy : 0;
        rowp[ky] = kv + ((size_t)b * HW_ + (size_t)yyc * 128) * C2_ + cbase;
    }
    uint4 win[3][3];
#pragma unroll
    for (int ky = 0; ky < 3; ky++) {
        win[ky][0] = (vy[ky] && x0 - 1 >= 0) ? *(const uint4*)(rowp[ky] + (size_t)(x0 - 1) * C2_) : zero4;
        win[ky][1] = vy[ky] ? *(const uint4*)(rowp[ky] + (size_t)x0 * C2_) : zero4;
    }
    for (int i = 0; i < 16; i++) {
        int x = x0 + i;
#pragma unroll
        for (int ky = 0; ky < 3; ky++)
            win[ky][2] = (vy[ky] && x + 1 <= 127) ? *(const uint4*)(rowp[ky] + (size_t)(x + 1) * C2_) : zero4;
        float acc[8];
#pragma unroll
        for (int j = 0; j < 8; j++) acc[j] = 0.f;
#pragma unroll
        for (int ky = 0; ky < 3; ky++)
#pragma unroll
            for (int kx = 0; kx < 3; kx++) {
                const bf16* pv = (const bf16*)&win[ky][kx];
#pragma unroll
                for (int j = 0; j < 8; j++)
                    acc[j] += fb(pv[j]) * wreg[ky * 3 + kx][j];
            }
        union { bf16 h[8]; uint4 u; } ov;
#pragma unroll
        for (int j = 0; j < 8; j++) ov.h[j] = tob(acc[j]);
        *(uint4*)(outb + (size_t)x * C_) = ov.u;
#pragma unroll
        for (int ky = 0; ky < 3; ky++) { win[ky][0] = win[ky][1]; win[ky][1] = win[ky][2]; }
    }
}

// ---------------- S partials + fused ssq: per (b,hd,chunk) over 256 positions ----------
__global__ __launch_bounds__(256) void k_qk(const bf16* __restrict__ q,
                                            const bf16* __restrict__ k,
                                            float* __restrict__ Spart,
                                            float* __restrict__ ssq) {
    __shared__ float qs[64][49];
    __shared__ float ks[64][49];
    __shared__ float redq[4][48], redk[4][48];
    int t = threadIdx.x;
    int ch = blockIdx.x, hd = blockIdx.y, b = blockIdx.z;
    int i0 = (t >> 4) * 3, j0 = (t & 15) * 3;
    int cs = t % 48, qr = t / 48;   // ssq ownership (t < 192)
    float acc[3][3];
    float sq = 0.f, sk = 0.f;
#pragma unroll
    for (int a = 0; a < 3; a++)
#pragma unroll
        for (int c = 0; c < 3; c++) acc[a][c] = 0.f;

    for (int sub = 0; sub < 4; sub++) {
        size_t rbase = ((size_t)b * HW_ + ch * 256 + sub * 64) * C_ + hd * 48;
        for (int i = t; i < 64 * 6; i += 256) {
            int row = i / 6, oc = i % 6;
            uint4 v = *(const uint4*)(q + rbase + (size_t)row * C_ + oc * 8);
            const bf16* pv = (const bf16*)&v;
#pragma unroll
            for (int j = 0; j < 8; j++) qs[row][oc * 8 + j] = fb(pv[j]);
            uint4 v2 = *(const uint4*)(k + rbase + (size_t)row * C_ + oc * 8);
            const bf16* pv2 = (const bf16*)&v2;
#pragma unroll
            for (int j = 0; j < 8; j++) ks[row][oc * 8 + j] = fb(pv2[j]);
        }
        __syncthreads();
        if (t < 192) {
#pragma unroll
            for (int rr = 0; rr < 16; rr++) {
                float qv = qs[qr * 16 + rr][cs]; sq += qv * qv;
                float kv2 = ks[qr * 16 + rr][cs]; sk += kv2 * kv2;
            }
        }
        for (int p = 0; p < 64; p++) {
            float a0 = qs[p][i0], a1 = qs[p][i0 + 1], a2 = qs[p][i0 + 2];
            float b0 = ks[p][j0], b1 = ks[p][j0 + 1], b2 = ks[p][j0 + 2];
            acc[0][0] += a0 * b0; acc[0][1] += a0 * b1; acc[0][2] += a0 * b2;
            acc[1][0] += a1 * b0; acc[1][1] += a1 * b1; acc[1][2] += a1 * b2;
            acc[2][0] += a2 * b0; acc[2][1] += a2 * b1; acc[2][2] += a2 * b2;
        }
        __syncthreads();
    }
    if (t < 192) { redq[qr][cs] = sq; redk[qr][cs] = sk; }
    float* dst = Spart + (((size_t)(b * 4 + hd)) * 64 + ch) * 2304;
#pragma unroll
    for (int a = 0; a < 3; a++)
#pragma unroll
        for (int c = 0; c < 3; c++) dst[(i0 + a) * 48 + (j0 + c)] = acc[a][c];
    __syncthreads();
    if (t < 48) {
        float s0 = redq[0][t] + redq[1][t] + redq[2][t] + redq[3][t];
        float s1 = redk[0][t] + redk[1][t] + redk[2][t] + redk[3][t];
        ssq[((size_t)b * 64 + ch) * C_ + hd * 48 + t] = s0;
        ssq[((size_t)(2 + b) * 64 + ch) * C_ + hd * 48 + t] = s1;
    }
}

// ---------------- softmax: reduce 64 chunks, fused inv-norms, emit block-diag bf16 W ---
__global__ __launch_bounds__(256) void k_softmax(const float* __restrict__ Spart,
                                                 const float* __restrict__ ssq,
                                                 const float* __restrict__ temp,
                                                 bf16* __restrict__ attnW) {
    __shared__ float S[2304];
    __shared__ float invk_s[48];
    int t = threadIdx.x;
    int hd = blockIdx.x, b = blockIdx.y;
    const float* base = Spart + ((size_t)(b * 4 + hd)) * 64 * 2304;
    for (int e = t; e < 2304; e += 256) {
        float s = 0.f;
        for (int ch = 0; ch < 64; ch++) s += base[(size_t)ch * 2304 + e];
        S[e] = s;
    }
    if (t < 48) {
        int c = hd * 48 + t;
        float sk = 0.f;
        for (int ch = 0; ch < 64; ch++) sk += ssq[((size_t)(2 + b) * 64 + ch) * C_ + c];
        invk_s[t] = 1.f / fmaxf(sqrtf(sk), 1e-12f);
    }
    __syncthreads();
    if (t >= 48) return;
    int c = hd * 48 + t;
    float sq = 0.f;
    for (int ch = 0; ch < 64; ch++) sq += ssq[((size_t)b * 64 + ch) * C_ + c];
    float qi = 1.f / fmaxf(sqrtf(sq), 1e-12f);
    float tp = temp[hd];
    float row[48];
    float mx = -1e30f;
    for (int j = 0; j < 48; j++) {
        float s = S[t * 48 + j] * qi * invk_s[j] * tp;
        row[j] = s;
        mx = fmaxf(mx, s);
    }
    float sum = 0.f;
    for (int j = 0; j < 48; j++) { row[j] = expf(row[j] - mx); sum += row[j]; }
    float is = 1.f / sum;
    bf16* wrow = attnW + ((size_t)b * 192 + hd * 48 + t) * 192;
    for (int blk4 = 0; blk4 < 4; blk4++)
        for (int j = 0; j < 48; j++)
            wrow[blk4 * 48 + j] = tob(blk4 == hd ? row[j] * is : 0.f);
}

// =====================================================================================
extern "C" void kernel_launch(void* const* d_in, const int* in_sizes, int n_in,
                              void* d_out, int out_size, void* d_ws, size_t ws_size,
                              hipStream_t stream) {
    const float* x     = (const float*)d_in[0];
    const float* illum = (const float*)d_in[1];
    const float* ln1w  = (const float*)d_in[2];
    const float* ln1b  = (const float*)d_in[3];
    const float* lnLw  = (const float*)d_in[4];
    const float* lnLb  = (const float*)d_in[5];
    const float* ln2w  = (const float*)d_in[6];
    const float* ln2b  = (const float*)d_in[7];
    const float* qw    = (const float*)d_in[8];
    const float* qdww  = (const float*)d_in[9];
    const float* kvw   = (const float*)d_in[10];
    const float* kvdww = (const float*)d_in[11];
    const float* temp  = (const float*)d_in[12];
    const float* projw = (const float*)d_in[13];
    const float* pinw  = (const float*)d_in[14];
    const float* dww   = (const float*)d_in[15];
    const float* poutw = (const float*)d_in[16];

    char* ws = (char*)d_ws;
    bf16*  Wq1   = (bf16*)(ws + 0);
    bf16*  Wkv   = (bf16*)(ws + 73728);
    bf16*  Wqdw  = (bf16*)(ws + 221184);
    bf16*  Wproj = (bf16*)(ws + 884736);
    bf16*  Wpin  = (bf16*)(ws + 958464);
    bf16*  Wdw   = (bf16*)(ws + 1155072);
    bf16*  Wpout = (bf16*)(ws + 5873664);
    float* ssq   = (float*)(ws + 6070272);   //  196,608
    char*  zpage = (char*)(ws + 6266880);    //    4,096
    const size_t A0 = 6270976, u = 12582912;
    bf16* xn    = (bf16*)(ws + A0 + 0 * u);   // [LN1, kv-gemm]
    bf16* iln   = (bf16*)(ws + A0 + 1 * u);   // [LNL, q-1x1]
    bf16* qtmp  = (bf16*)(ws + A0 + 2 * u);   // [q-1x1, q-3x3]
    bf16* qb    = (bf16*)(ws + A0 + 1 * u);   // [q-3x3, qk]
    bf16* kvtmp = (bf16*)(ws + A0 + 2 * u);   // [kv-gemm, dwconv] slots 2-3
    bf16* kb    = (bf16*)(ws + A0 + 0 * u);   // [dwconv, qk]
    bf16* vb    = (bf16*)(ws + A0 + 4 * u);   // [dwconv, av-gemm]
    float* Spart = (float*)(ws + A0 + 3 * u);          // [qk, softmax] 4.7 MB (slot 3)
    bf16*  attnW = (bf16*)(ws + A0 + 3 * u + 4718592); // [softmax, av-gemm] 147 KB
    bf16* outa  = (bf16*)(ws + A0 + 2 * u);   // [av-gemm, proj]
    bf16* x2    = (bf16*)(ws + A0 + 0 * u);   // [proj, pout]
    bf16* xn2   = (bf16*)(ws + A0 + 3 * u);   // [LN2, pin]
    bf16* fbuf  = (bf16*)(ws + A0 + 4 * u);   // [pin, dw3x3] 33.5 MB
    bf16* gbuf  = (bf16*)(ws + A0 + 1 * u);   // [dw3x3, pout] 33.5 MB (slots 1-3)
    // total = A0 + 4u + 33,554,432 = 90,157,056 bytes (~86 MB)

    // 0) all weight repacks + zero page in one launch
    k_repack_all<<<2513, 256, 0, stream>>>(qw, kvw, projw, pinw, poutw, qdww, dww,
                                           Wq1, Wkv, Wproj, Wpin, Wpout, Wqdw, Wdw, zpage);

    // 1) both NCHW LayerNorms fused
    k_ln_nchw<<<dim3(512, 2), 256, 0, stream>>>(x, illum, ln1w, ln1b, lnLw, lnLb, xn, iln);

    // 2) q = 1x1(iln) ; full 3x3 -> qb
    k_gemm1x1<96, 1><<<dim3(256, 2), 256, 0, stream>>>(iln, Wq1, 192, 192, qtmp, nullptr, 0);
    k_gemm3x3<96, 0><<<dim3(256, 2), 256, 0, stream>>>(qtmp, Wqdw, 192, 192, qb, zpage);

    // 3) kv = 1x1(xn) ; depthwise 3x3 -> kb, vb
    k_gemm1x1<128, 1><<<dim3(256, 3), 256, 0, stream>>>(xn, Wkv, 192, 384, kvtmp, nullptr, 0);
    k_dwconv2<<<dim3(256, 2), 192, 0, stream>>>(kvtmp, kvdww, kb, vb);

    // 4) attention (ssq fused into qk)
    k_qk<<<dim3(64, 4, 2), 256, 0, stream>>>(qb, kb, Spart, ssq);
    k_softmax<<<dim3(4, 2), 256, 0, stream>>>(Spart, ssq, temp, attnW);
    k_gemm1x1<96, 1><<<dim3(256, 2), 256, 0, stream>>>(vb, attnW, 192, 192, outa, nullptr, 36864);

    // 5) x2 = x + proj(out)
    k_gemm1x1<96, 2><<<dim3(256, 2), 256, 0, stream>>>(outa, Wproj, 192, 192, x2, x, 0);

    // 6) FFN
    k_ln_pc<<<512, 256, 0, stream>>>(x2, ln2w, ln2b, xn2);
    k_gemm1x1<128, 1><<<dim3(256, 4), 256, 0, stream>>>(xn2, Wpin, 192, 512, fbuf, nullptr, 0);
    k_gemm3x3<128, 1><<<dim3(256, 4), 256, 0, stream>>>(fbuf, Wdw, 512, 512, gbuf, zpage);
    k_gemm1x1<96, 3><<<dim3(256, 2), 256, 0, stream>>>(gbuf, Wpout, 512, 192, d_out, x2, 0);
}

// Round 10
// 371.757 us; speedup vs baseline: 1.5601x; 1.0243x over previous
//
#include <hip/hip_runtime.h>
#include <hip/hip_bf16.h>

typedef __hip_bfloat16 bf16;
typedef __attribute__((ext_vector_type(8))) short bf16x8v;
typedef __attribute__((ext_vector_type(4))) float f32x4;

namespace {
constexpr int B_  = 2;
constexpr int C_  = 192;
constexpr int HW_ = 128 * 128;   // 16384
constexpr int C2_ = 384;
}

static __device__ __forceinline__ float fb(bf16 v) { return __bfloat162float(v); }
static __device__ __forceinline__ bf16 tob(float v) { return __float2bfloat16(v); }

typedef __attribute__((address_space(1))) const char GChar;
typedef __attribute__((address_space(3))) char LChar;
static __device__ __forceinline__ void gl16(const void* g, void* l) {
    __builtin_amdgcn_global_load_lds((GChar*)g, (LChar*)l, 16, 0, 0);
}
static __device__ __forceinline__ bf16x8v lread(const bf16* base, int row, int slot) {
    const char* p = (const char*)base + (size_t)row * 128 + ((size_t)((slot ^ (row & 7))) << 4);
    return *(const bf16x8v*)p;
}

// ---------------- repack helpers ----------------
static __device__ __forceinline__ void rp1(const float* W, bf16* Wr, int blk, int t,
                                           int N, int K, int Npad, int Kpad) {
    int i = blk * 256 + t;
    if (i >= Npad * Kpad) return;
    int n = i / Kpad, k = i % Kpad;
    float v = (n < N && k < K) ? W[n * K + k] : 0.f;
    Wr[i] = tob(v);
}
static __device__ __forceinline__ void rp3(const float* W, bf16* Wr, int blk, int t,
                                           int N, int K, int Npad, int Kpad) {
    int i = blk * 256 + t;
    int NK = Npad * Kpad;
    if (i >= NK) return;
    int n = i / Kpad, k = i % Kpad;
    if (n < N && k < K) {
        const float* src = W + ((size_t)(n * K + k)) * 9;
#pragma unroll
        for (int q = 0; q < 9; q++) Wr[(size_t)q * NK + i] = tob(src[q]);
    } else {
#pragma unroll
        for (int q = 0; q < 9; q++) Wr[(size_t)q * NK + i] = tob(0.f);
    }
}

// ---------------- fused: all repacks + zero page + both NCHW LayerNorms ---------------
__global__ __launch_bounds__(256) void k_repack_ln(
    const float* __restrict__ qw, const float* __restrict__ kvw,
    const float* __restrict__ projw, const float* __restrict__ pinw,
    const float* __restrict__ poutw, const float* __restrict__ qdww,
    const float* __restrict__ dww,
    bf16* __restrict__ Wq1, bf16* __restrict__ Wkv, bf16* __restrict__ Wproj,
    bf16* __restrict__ Wpin, bf16* __restrict__ Wpout, bf16* __restrict__ Wqdw,
    bf16* __restrict__ Wdw, char* __restrict__ zpage,
    const float* __restrict__ X0, const float* __restrict__ X1,
    const float* __restrict__ w0, const float* __restrict__ b0,
    const float* __restrict__ w1, const float* __restrict__ b1,
    bf16* __restrict__ out0, bf16* __restrict__ out1) {
    __shared__ float lds[64][C_ + 1];
    int blk = blockIdx.x, t = threadIdx.x;
    if (blk < 144)        { rp1(qw,    Wq1,   blk,        t, 192, 192, 192, 192); return; }
    else if (blk < 432)   { rp1(kvw,   Wkv,   blk - 144,  t, 384, 192, 384, 192); return; }
    else if (blk < 576)   { rp1(projw, Wproj, blk - 432,  t, 192, 192, 192, 192); return; }
    else if (blk < 960)   { rp1(pinw,  Wpin,  blk - 576,  t, 510, 192, 512, 192); return; }
    else if (blk < 1344)  { rp1(poutw, Wpout, blk - 960,  t, 192, 510, 192, 512); return; }
    else if (blk < 1488)  { rp3(qdww,  Wqdw,  blk - 1344, t, 192, 192, 192, 192); return; }
    else if (blk < 2512)  { rp3(dww,   Wdw,   blk - 1488, t, 510, 510, 512, 512); return; }
    else if (blk == 2512) { ((uint4*)zpage)[t] = make_uint4(0u, 0u, 0u, 0u); return; }
    // LayerNorm blocks: lb in [0, 1024)
    int lb = blk - 2513;
    int sel = lb >> 9, xb = lb & 511;
    const float* X = sel ? X1 : X0;
    const float* w = sel ? w1 : w0;
    const float* bb = sel ? b1 : b0;
    bf16* out = sel ? out1 : out0;
    int p0 = xb * 64;
    int b = p0 / HW_, pi0 = p0 % HW_;
    for (int i = t; i < 64 * C_ / 4; i += 256) {
        int c = i >> 4, pp4 = (i & 15) << 2;
        float4 v = *(const float4*)(X + ((size_t)(b * C_ + c)) * HW_ + pi0 + pp4);
        lds[pp4 + 0][c] = v.x; lds[pp4 + 1][c] = v.y;
        lds[pp4 + 2][c] = v.z; lds[pp4 + 3][c] = v.w;
    }
    __syncthreads();
    int pp = t >> 2, qq = t & 3;
    float s = 0.f, s2 = 0.f;
    for (int c = qq * 48; c < qq * 48 + 48; c++) { float v = lds[pp][c]; s += v; s2 += v * v; }
    s  += __shfl_xor(s, 1);  s  += __shfl_xor(s, 2);
    s2 += __shfl_xor(s2, 1); s2 += __shfl_xor(s2, 2);
    float mu = s / C_;
    float rstd = rsqrtf(s2 / C_ - mu * mu + 1e-5f);
    bf16* ob = out + ((size_t)(p0 + pp)) * C_ + qq * 48;
#pragma unroll
    for (int j = 0; j < 6; j++) {
        union { bf16 h[8]; uint4 u; } ov;
#pragma unroll
        for (int e = 0; e < 8; e++) {
            int c = qq * 48 + j * 8 + e;
            ov.h[e] = tob((lds[pp][c] - mu) * rstd * w[c] + bb[c]);
        }
        *(uint4*)(ob + j * 8) = ov.u;
    }
}

// LayerNorm from [p][c] bf16 -> [p][c] bf16 (vectorized)
__global__ __launch_bounds__(256) void k_ln_pc(const bf16* __restrict__ X2,
                                               const float* __restrict__ w,
                                               const float* __restrict__ bb,
                                               bf16* __restrict__ out) {
    int t = threadIdx.x;
    int p = blockIdx.x * 64 + (t >> 2), qq = t & 3;
    const bf16* row = X2 + (size_t)p * C_ + qq * 48;
    uint4 u[6];
#pragma unroll
    for (int j = 0; j < 6; j++) u[j] = *(const uint4*)(row + j * 8);
    float s = 0.f, s2 = 0.f;
#pragma unroll
    for (int j = 0; j < 6; j++) {
        const bf16* pv = (const bf16*)&u[j];
#pragma unroll
        for (int e = 0; e < 8; e++) { float v = fb(pv[e]); s += v; s2 += v * v; }
    }
    s  += __shfl_xor(s, 1);  s  += __shfl_xor(s, 2);
    s2 += __shfl_xor(s2, 1); s2 += __shfl_xor(s2, 2);
    float mu = s / C_;
    float rstd = rsqrtf(s2 / C_ - mu * mu + 1e-5f);
    bf16* orow = out + (size_t)p * C_ + qq * 48;
#pragma unroll
    for (int j = 0; j < 6; j++) {
        const bf16* pv = (const bf16*)&u[j];
        union { bf16 h[8]; uint4 u4; } ov;
#pragma unroll
        for (int e = 0; e < 8; e++) {
            int c = qq * 48 + j * 8 + e;
            ov.h[e] = tob((fb(pv[e]) - mu) * rstd * w[c] + bb[c]);
        }
        *(uint4*)(orow + j * 8) = ov.u4;
    }
}

// ---------------- 1x1 conv GEMM body (global_load_lds + swizzle), BK=64 ---------------
// EPI: 1 = plain bf16 [p][Cout]; 2 = +resid(NCHW f32) -> bf16 [p][C_];
//      3 = +resid(bf16 [p][C_]) -> f32 NCHW
template <int BN, int EPI>
static __device__ __forceinline__ void gemm1x1_body(const bf16* __restrict__ A,
                                                    const bf16* __restrict__ Wbase,
                                                    const int K, const int Cout,
                                                    void* __restrict__ outp,
                                                    const void* __restrict__ resid,
                                                    const int mt, const int n0) {
    constexpr int WN = BN / 2, FN = WN / 16, BIT = BN / 32;
    __shared__ __align__(16) bf16 As[128 * 64];
    __shared__ __align__(16) bf16 Bs[BN * 64];
    const int t = threadIdx.x;
    const int b = mt >> 7, y = mt & 127;
    const int w = t >> 6, lane = t & 63;
    const int wm = w >> 1, wn = w & 1;
    const int g = lane >> 4, r = lane & 15;
    const int ldw = t - lane;

    f32x4 acc[4][FN];
#pragma unroll
    for (int i = 0; i < 4; i++)
#pragma unroll
        for (int j = 0; j < FN; j++) acc[i][j] = {0.f, 0.f, 0.f, 0.f};

    const bf16* Abase = A + (size_t)mt * 128 * K;

    for (int c0 = 0; c0 < K; c0 += 64) {
#pragma unroll
        for (int it = 0; it < 4; it++) {
            int idx = it * 256 + t;
            int row = idx >> 3, sl = idx & 7;
            const char* gp = (const char*)(Abase + (size_t)row * K + c0) + ((sl ^ (row & 7)) << 4);
            gl16(gp, (char*)As + (size_t)(it * 256 + ldw) * 16);
        }
#pragma unroll
        for (int it = 0; it < BIT; it++) {
            int idx = it * 256 + t;
            int row = idx >> 3, sl = idx & 7;
            const char* gp = (const char*)(Wbase + (size_t)(n0 + row) * K + c0) + ((sl ^ (row & 7)) << 4);
            gl16(gp, (char*)Bs + (size_t)(it * 256 + ldw) * 16);
        }
        __syncthreads();
#pragma unroll
        for (int ks = 0; ks < 2; ks++) {
            bf16x8v af[4], bv[FN];
#pragma unroll
            for (int fm = 0; fm < 4; fm++)
                af[fm] = lread(As, wm * 64 + fm * 16 + r, ks * 4 + g);
#pragma unroll
            for (int fn = 0; fn < FN; fn++)
                bv[fn] = lread(Bs, wn * WN + fn * 16 + r, ks * 4 + g);
#pragma unroll
            for (int fm = 0; fm < 4; fm++)
#pragma unroll
                for (int fn = 0; fn < FN; fn++)
                    acc[fm][fn] = __builtin_amdgcn_mfma_f32_16x16x32_bf16(af[fm], bv[fn], acc[fm][fn], 0, 0, 0);
        }
        __syncthreads();
    }

#pragma unroll
    for (int fm = 0; fm < 4; fm++)
#pragma unroll
        for (int fn = 0; fn < FN; fn++)
#pragma unroll
            for (int reg = 0; reg < 4; reg++) {
                int xl = wm * 64 + fm * 16 + g * 4 + reg;
                int co = n0 + wn * WN + fn * 16 + r;
                float v = acc[fm][fn][reg];
                if constexpr (EPI == 1) {
                    ((bf16*)outp)[((size_t)mt * 128 + xl) * Cout + co] = tob(v);
                } else if constexpr (EPI == 2) {
                    v += ((const float*)resid)[((size_t)(b * C_ + co)) * HW_ + y * 128 + xl];
                    ((bf16*)outp)[((size_t)mt * 128 + xl) * C_ + co] = tob(v);
                } else {
                    v += fb(((const bf16*)resid)[((size_t)mt * 128 + xl) * C_ + co]);
                    ((float*)outp)[((size_t)(b * C_ + co)) * HW_ + y * 128 + xl] = v;
                }
            }
}

template <int BN, int EPI>
__global__ __launch_bounds__(256) void k_gemm1x1(const bf16* __restrict__ A,
                                                 const bf16* __restrict__ Wr,
                                                 const int K, const int Cout,
                                                 void* __restrict__ outp,
                                                 const void* __restrict__ resid,
                                                 const int wbstride) {
    const int mt = blockIdx.x;
    const bf16* Wbase = Wr + (size_t)(mt >> 7) * wbstride;
    gemm1x1_body<BN, EPI>(A, Wbase, K, Cout, outp, resid, mt, blockIdx.y * BN);
}

// fused q-1x1 (y 0..1) + kv-1x1 (y 2..5), both BN=96, K=192
__global__ __launch_bounds__(256) void k_qkv(const bf16* __restrict__ iln,
                                             const bf16* __restrict__ xn,
                                             const bf16* __restrict__ Wq1,
                                             const bf16* __restrict__ Wkv,
                                             bf16* __restrict__ qtmp,
                                             bf16* __restrict__ kvtmp) {
    const bool isq = blockIdx.y < 2;
    const bf16* A = isq ? iln : xn;
    const bf16* Wr = isq ? Wq1 : Wkv;
    bf16* outp = isq ? qtmp : kvtmp;
    const int Cout = isq ? 192 : 384;
    const int n0 = (isq ? blockIdx.y : blockIdx.y - 2) * 96;
    gemm1x1_body<96, 1>(A, Wr, 192, Cout, outp, nullptr, blockIdx.x, n0);
}

// ---------------- 3x3 full conv implicit GEMM, simple 2-barrier + XCD mt-swizzle ------
template <int BN, int EPI>
__global__ __launch_bounds__(256) void k_gemm3x3(const bf16* __restrict__ A,
                                                 const bf16* __restrict__ Wr,
                                                 const int Cin, const int Cout,
                                                 bf16* __restrict__ outp,
                                                 const char* __restrict__ zpage) {
    constexpr int WN = BN / 2, FN = WN / 16, BIT = BN / 32;
    __shared__ __align__(16) bf16 As[160 * 64];
    __shared__ __align__(16) bf16 Bs[BN * 64];
    const int t = threadIdx.x;
    const int mtRaw = blockIdx.x;
    const int mt = ((mtRaw & 7) << 5) | (mtRaw >> 3);   // XCD-contiguous rows
    const int n0 = blockIdx.y * BN;
    const int b = mt >> 7, y = mt & 127;
    const int w = t >> 6, lane = t & 63;
    const int wm = w >> 1, wn = w & 1;
    const int g = lane >> 4, r = lane & 15;
    const int ldw = t - lane;

    f32x4 acc[4][FN];
#pragma unroll
    for (int i = 0; i < 4; i++)
#pragma unroll
        for (int j = 0; j < FN; j++) acc[i][j] = {0.f, 0.f, 0.f, 0.f};

    for (int ky = 0; ky < 3; ky++) {
        const int yy = y + ky - 1;
        if (yy < 0 || yy > 127) continue;   // block-uniform
        const bf16* Ab = A + ((size_t)b * HW_ + (size_t)yy * 128) * Cin;
        for (int c0 = 0; c0 < Cin; c0 += 64) {
            for (int kx = 0; kx < 3; kx++) {
                if (kx == 0) {
#pragma unroll
                    for (int it = 0; it < 5; it++) {
                        int idx = it * 256 + t;
                        int row = idx >> 3, sl = idx & 7;
                        int so = (sl ^ (row & 7)) << 4;
                        const char* gp = (row >= 1 && row <= 128)
                            ? (const char*)(Ab + (size_t)(row - 1) * Cin + c0) + so
                            : zpage + so;
                        gl16(gp, (char*)As + (size_t)(it * 256 + ldw) * 16);
                    }
                }
                const bf16* Wb = Wr + (size_t)(ky * 3 + kx) * Cout * Cin;
#pragma unroll
                for (int it = 0; it < BIT; it++) {
                    int idx = it * 256 + t;
                    int row = idx >> 3, sl = idx & 7;
                    const char* gp = (const char*)(Wb + (size_t)(n0 + row) * Cin + c0) + ((sl ^ (row & 7)) << 4);
                    gl16(gp, (char*)Bs + (size_t)(it * 256 + ldw) * 16);
                }
                __syncthreads();
#pragma unroll
                for (int ks = 0; ks < 2; ks++) {
                    bf16x8v af[4], bv[FN];
#pragma unroll
                    for (int fm = 0; fm < 4; fm++)
                        af[fm] = lread(As, wm * 64 + fm * 16 + r + kx, ks * 4 + g);
#pragma unroll
                    for (int fn = 0; fn < FN; fn++)
                        bv[fn] = lread(Bs, wn * WN + fn * 16 + r, ks * 4 + g);
#pragma unroll
                    for (int fm = 0; fm < 4; fm++)
#pragma unroll
                        for (int fn = 0; fn < FN; fn++)
                            acc[fm][fn] = __builtin_amdgcn_mfma_f32_16x16x32_bf16(af[fm], bv[fn], acc[fm][fn], 0, 0, 0);
                }
                __syncthreads();
            }
        }
    }
#pragma unroll
    for (int fm = 0; fm < 4; fm++)
#pragma unroll
        for (int fn = 0; fn < FN; fn++)
#pragma unroll
            for (int reg = 0; reg < 4; reg++) {
                int xl = wm * 64 + fm * 16 + g * 4 + reg;
                int co = n0 + wn * WN + fn * 16 + r;
                float v = acc[fm][fn][reg];
                if constexpr (EPI == 1) v = 0.5f * v * (1.0f + erff(v * 0.70710678118654752f));
                outp[((size_t)mt * 128 + xl) * Cout + co] = tob(v);
            }
}

// ---------------- depthwise 3x3: sliding-window cols, 16 contiguous x per thread -------
__global__ __launch_bounds__(192) void k_dwconv2(const bf16* __restrict__ kv,
                                                 const float* __restrict__ wdw,
                                                 bf16* __restrict__ kout,
                                                 bf16* __restrict__ vout) {
    __shared__ float wlds[1728];
    const int t = threadIdx.x;
    const int row = blockIdx.x;
    const int z = blockIdx.y;
    const int b = row >> 7, y = row & 127;
    for (int i = t; i < 432; i += 192)
        ((float4*)wlds)[i] = ((const float4*)(wdw + (size_t)z * 1728))[i];
    __syncthreads();
    const int c8h = t % 24, xg = t / 24;
    const int cbase = z * C_ + c8h * 8;
    float wreg[9][8];
#pragma unroll
    for (int tap = 0; tap < 9; tap++)
#pragma unroll
        for (int j = 0; j < 8; j++) wreg[tap][j] = wlds[(c8h * 8 + j) * 9 + tap];

    bf16* outb = (z == 0 ? kout : vout) + (size_t)(b * HW_ + y * 128) * C_ + c8h * 8;
    const uint4 zero4 = make_uint4(0u, 0u, 0u, 0u);
    const int x0 = xg * 16;
    bool vy[3]; const bf16* rowp[3];
#pragma unroll
    for (int ky = 0; ky < 3; ky++) {
        int yy = y + ky - 1;
        vy[ky] = (yy >= 0 && yy <= 127);
        int yyc = vy[ky] ? yy : 0;
        rowp[ky] = kv + ((size_t)b * HW_ + (size_t)yyc * 128) * C2_ + cbase;
    }
    uint4 win[3][3];
#pragma unroll
    for (int ky = 0; ky < 3; ky++) {
        win[ky][0] = (vy[ky] && x0 - 1 >= 0) ? *(const uint4*)(rowp[ky] + (size_t)(x0 - 1) * C2_) : zero4;
        win[ky][1] = vy[ky] ? *(const uint4*)(rowp[ky] + (size_t)x0 * C2_) : zero4;
    }
    for (int i = 0; i < 16; i++) {
        int x = x0 + i;
#pragma unroll
        for (int ky = 0; ky < 3; ky++)
            win[ky][2] = (vy[ky] && x + 1 <= 127) ? *(const uint4*)(rowp[ky] + (size_t)(x + 1) * C2_) : zero4;
        float acc[8];
#pragma unroll
        for (int j = 0; j < 8; j++) acc[j] = 0.f;
#pragma unroll
        for (int ky = 0; ky < 3; ky++)
#pragma unroll
            for (int kx = 0; kx < 3; kx++) {
                const bf16* pv = (const bf16*)&win[ky][kx];
#pragma unroll
                for (int j = 0; j < 8; j++)
                    acc[j] += fb(pv[j]) * wreg[ky * 3 + kx][j];
            }
        union { bf16 h[8]; uint4 u; } ov;
#pragma unroll
        for (int j = 0; j < 8; j++) ov.h[j] = tob(acc[j]);
        *(uint4*)(outb + (size_t)x * C_) = ov.u;
#pragma unroll
        for (int ky = 0; ky < 3; ky++) { win[ky][0] = win[ky][1]; win[ky][1] = win[ky][2]; }
    }
}

// ---------------- S partials + fused ssq: per (b,hd,chunk) over 256 positions ----------
__global__ __launch_bounds__(256) void k_qk(const bf16* __restrict__ q,
                                            const bf16* __restrict__ k,
                                            float* __restrict__ Spart,
                                            float* __restrict__ ssq) {
    __shared__ float qs[64][49];
    __shared__ float ks[64][49];
    __shared__ float redq[4][48], redk[4][48];
    int t = threadIdx.x;
    int ch = blockIdx.x, hd = blockIdx.y, b = blockIdx.z;
    int i0 = (t >> 4) * 3, j0 = (t & 15) * 3;
    int cs = t % 48, qr = t / 48;
    float acc[3][3];
    float sq = 0.f, sk = 0.f;
#pragma unroll
    for (int a = 0; a < 3; a++)
#pragma unroll
        for (int c = 0; c < 3; c++) acc[a][c] = 0.f;

    for (int sub = 0; sub < 4; sub++) {
        size_t rbase = ((size_t)b * HW_ + ch * 256 + sub * 64) * C_ + hd * 48;
        for (int i = t; i < 64 * 6; i += 256) {
            int row = i / 6, oc = i % 6;
            uint4 v = *(const uint4*)(q + rbase + (size_t)row * C_ + oc * 8);
            const bf16* pv = (const bf16*)&v;
#pragma unroll
            for (int j = 0; j < 8; j++) qs[row][oc * 8 + j] = fb(pv[j]);
            uint4 v2 = *(const uint4*)(k + rbase + (size_t)row * C_ + oc * 8);
            const bf16* pv2 = (const bf16*)&v2;
#pragma unroll
            for (int j = 0; j < 8; j++) ks[row][oc * 8 + j] = fb(pv2[j]);
        }
        __syncthreads();
        if (t < 192) {
#pragma unroll
            for (int rr = 0; rr < 16; rr++) {
                float qv = qs[qr * 16 + rr][cs]; sq += qv * qv;
                float kv2 = ks[qr * 16 + rr][cs]; sk += kv2 * kv2;
            }
        }
        for (int p = 0; p < 64; p++) {
            float a0 = qs[p][i0], a1 = qs[p][i0 + 1], a2 = qs[p][i0 + 2];
            float b0 = ks[p][j0], b1 = ks[p][j0 + 1], b2 = ks[p][j0 + 2];
            acc[0][0] += a0 * b0; acc[0][1] += a0 * b1; acc[0][2] += a0 * b2;
            acc[1][0] += a1 * b0; acc[1][1] += a1 * b1; acc[1][2] += a1 * b2;
            acc[2][0] += a2 * b0; acc[2][1] += a2 * b1; acc[2][2] += a2 * b2;
        }
        __syncthreads();
    }
    if (t < 192) { redq[qr][cs] = sq; redk[qr][cs] = sk; }
    float* dst = Spart + (((size_t)(b * 4 + hd)) * 64 + ch) * 2304;
#pragma unroll
    for (int a = 0; a < 3; a++)
#pragma unroll
        for (int c = 0; c < 3; c++) dst[(i0 + a) * 48 + (j0 + c)] = acc[a][c];
    __syncthreads();
    if (t < 48) {
        float s0 = redq[0][t] + redq[1][t] + redq[2][t] + redq[3][t];
        float s1 = redk[0][t] + redk[1][t] + redk[2][t] + redk[3][t];
        ssq[((size_t)b * 64 + ch) * C_ + hd * 48 + t] = s0;
        ssq[((size_t)(2 + b) * 64 + ch) * C_ + hd * 48 + t] = s1;
    }
}

// ---------------- softmax: reduce 64 chunks, fused inv-norms, emit diag-block bf16 ----
__global__ __launch_bounds__(256) void k_softmax(const float* __restrict__ Spart,
                                                 const float* __restrict__ ssq,
                                                 const float* __restrict__ temp,
                                                 bf16* __restrict__ attnW) {
    __shared__ float S[2304];
    __shared__ float invk_s[48];
    int t = threadIdx.x;
    int hd = blockIdx.x, b = blockIdx.y;
    const float* base = Spart + ((size_t)(b * 4 + hd)) * 64 * 2304;
    for (int e = t; e < 2304; e += 256) {
        float s = 0.f;
        for (int ch = 0; ch < 64; ch++) s += base[(size_t)ch * 2304 + e];
        S[e] = s;
    }
    if (t < 48) {
        int c = hd * 48 + t;
        float sk = 0.f;
        for (int ch = 0; ch < 64; ch++) sk += ssq[((size_t)(2 + b) * 64 + ch) * C_ + c];
        invk_s[t] = 1.f / fmaxf(sqrtf(sk), 1e-12f);
    }
    __syncthreads();
    if (t >= 48) return;
    int c = hd * 48 + t;
    float sq = 0.f;
    for (int ch = 0; ch < 64; ch++) sq += ssq[((size_t)b * 64 + ch) * C_ + c];
    float qi = 1.f / fmaxf(sqrtf(sq), 1e-12f);
    float tp = temp[hd];
    float row[48];
    float mx = -1e30f;
    for (int j = 0; j < 48; j++) {
        float s = S[t * 48 + j] * qi * invk_s[j] * tp;
        row[j] = s;
        mx = fmaxf(mx, s);
    }
    float sum = 0.f;
    for (int j = 0; j < 48; j++) { row[j] = expf(row[j] - mx); sum += row[j]; }
    float is = 1.f / sum;
    // only the diagonal block is ever read by k_wav
    bf16* wrow = attnW + ((size_t)b * 192 + hd * 48 + t) * 192 + hd * 48;
    for (int j = 0; j < 48; j++) wrow[j] = tob(row[j] * is);
}

// ---------------- M[b][c2][c0] = sum_{c1 in head(c0)} Wproj[c2][c1]*attn[b][c1][c0] ----
__global__ __launch_bounds__(256) void k_wav(const bf16* __restrict__ Wproj,
                                             const bf16* __restrict__ attnW,
                                             bf16* __restrict__ Mw) {
    int bid = blockIdx.x;            // 24 = b*12 + rg
    int b = bid / 12, rg = bid % 12;
    int t = threadIdx.x;
    int row = rg * 16 + (t >> 4);    // c2
    int c0b = (t & 15) * 12;         // 12 cols, all within one head
    int hd = c0b / 48;
    const bf16* aw = attnW + (size_t)b * 36864;
    float acc[12];
#pragma unroll
    for (int j = 0; j < 12; j++) acc[j] = 0.f;
    for (int k = hd * 48; k < hd * 48 + 48; k++) {
        float wp = fb(Wproj[row * 192 + k]);
        const bf16* ar = aw + (size_t)k * 192 + c0b;
#pragma unroll
        for (int j = 0; j < 12; j++) acc[j] += wp * fb(ar[j]);
    }
    bf16* mrow = Mw + ((size_t)b * 192 + row) * 192 + c0b;
#pragma unroll
    for (int j = 0; j < 12; j++) mrow[j] = tob(acc[j]);
}

// =====================================================================================
extern "C" void kernel_launch(void* const* d_in, const int* in_sizes, int n_in,
                              void* d_out, int out_size, void* d_ws, size_t ws_size,
                              hipStream_t stream) {
    const float* x     = (const float*)d_in[0];
    const float* illum = (const float*)d_in[1];
    const float* ln1w  = (const float*)d_in[2];
    const float* ln1b  = (const float*)d_in[3];
    const float* lnLw  = (const float*)d_in[4];
    const float* lnLb  = (const float*)d_in[5];
    const float* ln2w  = (const float*)d_in[6];
    const float* ln2b  = (const float*)d_in[7];
    const float* qw    = (const float*)d_in[8];
    const float* qdww  = (const float*)d_in[9];
    const float* kvw   = (const float*)d_in[10];
    const float* kvdww = (const float*)d_in[11];
    const float* temp  = (const float*)d_in[12];
    const float* projw = (const float*)d_in[13];
    const float* pinw  = (const float*)d_in[14];
    const float* dww   = (const float*)d_in[15];
    const float* poutw = (const float*)d_in[16];

    char* ws = (char*)d_ws;
    bf16*  Wq1   = (bf16*)(ws + 0);
    bf16*  Wkv   = (bf16*)(ws + 73728);
    bf16*  Wqdw  = (bf16*)(ws + 221184);
    bf16*  Wproj = (bf16*)(ws + 884736);
    bf16*  Wpin  = (bf16*)(ws + 958464);
    bf16*  Wdw   = (bf16*)(ws + 1155072);
    bf16*  Wpout = (bf16*)(ws + 5873664);
    float* ssq   = (float*)(ws + 6070272);   //  196,608
    char*  zpage = (char*)(ws + 6266880);    //    4,096
    const size_t A0 = 6270976, u = 12582912;
    bf16* xn    = (bf16*)(ws + A0 + 0 * u);   // [LN1, qkv]
    bf16* iln   = (bf16*)(ws + A0 + 1 * u);   // [LNL, qkv]
    bf16* qtmp  = (bf16*)(ws + A0 + 2 * u);   // [qkv, q-3x3]
    bf16* qb    = (bf16*)(ws + A0 + 1 * u);   // [q-3x3, qk]
    bf16* kvtmp = (bf16*)(ws + A0 + 2 * u);   // wait -- see below
    // NOTE: kvtmp needs 2 slots and must not alias qtmp (q path reads qtmp after kv
    // written). Keep round-9 layout: qtmp in slot 2, kvtmp in slots 2-3 is WRONG if
    // both live. Round-9 worked because q-3x3 consumed qtmp BEFORE kv-gemm wrote
    // kvtmp. With fused qkv they are written together -> give qtmp its own slot.
    // Layout now: slot2+3 = kvtmp (25.2MB), qtmp = slot4-lo (12.6MB of 33.5MB region).
    bf16* vb    = (bf16*)(ws + A0 + 4 * u);
    float* Spart = (float*)(ws + A0 + 3 * u);
    bf16*  attnW = (bf16*)(ws + A0 + 3 * u + 4718592);
    bf16*  Mw    = (bf16*)(ws + A0 + 3 * u + 4866048);
    bf16* kb    = (bf16*)(ws + A0 + 0 * u);
    bf16* x2    = (bf16*)(ws + A0 + 0 * u);
    bf16* xn2   = (bf16*)(ws + A0 + 3 * u);
    bf16* fbuf  = (bf16*)(ws + A0 + 4 * u);
    bf16* gbuf  = (bf16*)(ws + A0 + 1 * u);
    // Fix aliasing for fused qkv (see note): qtmp -> slot 4+1u region start
    qtmp  = (bf16*)(ws + A0 + 4 * u);            // [qkv, q-3x3]
    kvtmp = (bf16*)(ws + A0 + 2 * u);            // [qkv, dwconv] slots 2-3
    qb    = (bf16*)(ws + A0 + 1 * u);            // [q-3x3, qk] (iln dead after qkv)
    vb    = (bf16*)(ws + A0 + 4 * u + 12582912); // [dwconv, proj-gemm] slot4-hi
    // fbuf (pin output, 33.5MB) reuses slot 4 region AFTER vb dead: pin runs after
    // proj-gemm (vb last read there) -> safe.
    // Spart (slot 3) overlaps kvtmp-hi: qk runs AFTER dwconv consumed kvtmp -> safe.
    // total ws = A0 + 4u + 33,554,432 (unchanged ~86 MB)

    // 0) repacks + zpage + both NCHW LayerNorms, one launch
    k_repack_ln<<<3537, 256, 0, stream>>>(qw, kvw, projw, pinw, poutw, qdww, dww,
                                          Wq1, Wkv, Wproj, Wpin, Wpout, Wqdw, Wdw, zpage,
                                          x, illum, ln1w, ln1b, lnLw, lnLb, xn, iln);

    // 1) q-1x1 + kv-1x1 fused
    k_qkv<<<dim3(256, 6), 256, 0, stream>>>(iln, xn, Wq1, Wkv, qtmp, kvtmp);

    // 2) q full 3x3 -> qb ; kv depthwise -> kb, vb
    k_gemm3x3<96, 0><<<dim3(256, 2), 256, 0, stream>>>(qtmp, Wqdw, 192, 192, qb, zpage);
    k_dwconv2<<<dim3(256, 2), 192, 0, stream>>>(kvtmp, kvdww, kb, vb);

    // 3) attention
    k_qk<<<dim3(64, 4, 2), 256, 0, stream>>>(qb, kb, Spart, ssq);
    k_softmax<<<dim3(4, 2), 256, 0, stream>>>(Spart, ssq, temp, attnW);
    k_wav<<<24, 256, 0, stream>>>(Wproj, attnW, Mw);

    // 4) x2 = x + v @ (proj∘attn)
    k_gemm1x1<96, 2><<<dim3(256, 2), 256, 0, stream>>>(vb, Mw, 192, 192, x2, x, 36864);

    // 5) FFN
    k_ln_pc<<<512, 256, 0, stream>>>(x2, ln2w, ln2b, xn2);
    k_gemm1x1<128, 1><<<dim3(256, 4), 256, 0, stream>>>(xn2, Wpin, 192, 512, fbuf, nullptr, 0);
    k_gemm3x3<128, 1><<<dim3(256, 4), 256, 0, stream>>>(fbuf, Wdw, 512, 512, gbuf, zpage);
    k_gemm1x1<96, 3><<<dim3(256, 2), 256, 0, stream>>>(gbuf, Wpout, 512, 192, d_out, x2, 0);
}